// Round 4
// baseline (1418.007 us; speedup 1.0000x reference)
//
#include <hip/hip_runtime.h>

#define NNODES 50000
#define NEDGES 400000
#define NMOLS  2000
#define NBLK   196   // ceil(NNODES/256)

// ---- ws layout (4-byte units) ----
constexpr size_t OFF_CNT   = 0;         // 50000 int (zeroed each call)
constexpr size_t OFF_OFFS  = 50000;     // 50000 int
constexpr size_t OFF_CURS  = 100000;    // 50000 int
constexpr size_t OFF_BSUM  = 150000;    // 256 int
constexpr size_t OFF_SRCS  = 150256;    // 400000 int (CSR-ordered src)
constexpr size_t OFF_EB    = 550256;    // 400000*12 floats (b[9] + pad, CSR-ordered)
constexpr size_t OFF_G     = 5350256;   // 50000*28 floats (26 used)
constexpr size_t OFF_NF1   = 6750256;   // 50000*56 floats (54 used)
constexpr size_t OFF_HH    = 9550256;   // 50000*12 floats (9 used)
// end 10150256 * 4B = 40.6 MB

__device__ __forceinline__ void make_b(float w0, float dx, float dy, float dz, float* b) {
  const float s3 = 1.7320508075688772f, s5c = 2.2360679774997896f, s15 = 3.872983346207417f;
  float r2 = dx * dx + dy * dy + dz * dz;
  b[0] = w0;
  b[1] = w0 * s3 * dy;
  b[2] = w0 * s3 * dz;
  b[3] = w0 * s3 * dx;
  b[4] = w0 * s15 * dx * dy;
  b[5] = w0 * s15 * dy * dz;
  b[6] = w0 * 0.5f * s5c * (3.f * dz * dz - r2);
  b[7] = w0 * s15 * dx * dz;
  b[8] = w0 * 0.5f * s15 * (dx * dx - dy * dy);
}

// ---------- CSR build ----------
__global__ void k_count(const int* __restrict__ dst, int* __restrict__ cnt) {
  int e = blockIdx.x * blockDim.x + threadIdx.x;
  if (e < NEDGES) atomicAdd(cnt + dst[e], 1);
}

__global__ void k_scanA(const int* __restrict__ cnt, int* __restrict__ offs, int* __restrict__ bsum) {
  __shared__ int sh[256];
  int t = threadIdx.x, i = blockIdx.x * 256 + t;
  int c = (i < NNODES) ? cnt[i] : 0;
  sh[t] = c; __syncthreads();
  #pragma unroll
  for (int off = 1; off < 256; off <<= 1) {
    int v = (t >= off) ? sh[t - off] : 0; __syncthreads();
    sh[t] += v; __syncthreads();
  }
  if (i < NNODES) offs[i] = sh[t] - c;
  if (t == 255) bsum[blockIdx.x] = sh[255];
}

__global__ void k_scanB(int* __restrict__ bsum) {
  __shared__ int sh[256];
  int t = threadIdx.x;
  int v = (t < NBLK) ? bsum[t] : 0;
  sh[t] = v; __syncthreads();
  #pragma unroll
  for (int off = 1; off < 256; off <<= 1) {
    int u = (t >= off) ? sh[t - off] : 0; __syncthreads();
    sh[t] += u; __syncthreads();
  }
  bsum[t] = sh[t] - v;
}

__global__ void k_scanC(int* __restrict__ offs, int* __restrict__ curs, const int* __restrict__ bsum) {
  int i = blockIdx.x * 256 + threadIdx.x;
  if (i < NNODES) {
    int o = offs[i] + bsum[blockIdx.x];
    offs[i] = o;
    curs[i] = o;
  }
}

// fill CSR slots: src index + precomputed b[9] (edge SH * edge_attr[:,0])
__global__ void k_fill(const float* __restrict__ pos, const float* __restrict__ ea,
                       const int* __restrict__ src, const int* __restrict__ dst,
                       int* __restrict__ curs, int* __restrict__ srcs, float* __restrict__ eb) {
  int e = blockIdx.x * blockDim.x + threadIdx.x;
  if (e >= NEDGES) return;
  int s = src[e], d = dst[e];
  int p = atomicAdd(curs + d, 1);
  srcs[p] = s;
  float dx = pos[3 * s] - pos[3 * d];
  float dy = pos[3 * s + 1] - pos[3 * d + 1];
  float dz = pos[3 * s + 2] - pos[3 * d + 2];
  float b[9];
  make_b(ea[(size_t)e * 7], dx, dy, dz, b);
  float4* o = (float4*)(eb + (size_t)p * 12);
  o[0] = make_float4(b[0], b[1], b[2], b[3]);
  o[1] = make_float4(b[4], b[5], b[6], b[7]);
  o[2] = make_float4(b[8], 0.f, 0.f, 0.f);
}

// ---------- node linear + TP1 precompute ----------
__global__ void k_node1(const float* __restrict__ x, const float* __restrict__ lw,
                        const float* __restrict__ lb, const float* __restrict__ w1,
                        float* __restrict__ g) {
  int n = blockIdx.x * blockDim.x + threadIdx.x;
  if (n >= NNODES) return;
  float f[23];
  const float* xr = x + (size_t)n * 23;
  #pragma unroll
  for (int v = 0; v < 23; ++v) {
    float acc = lb[v];
    const float* wr = lw + v * 23;
    #pragma unroll
    for (int c = 0; c < 23; ++c) acc += xr[c] * wr[c];
    f[v] = fmaxf(acc, 0.f);
  }
  float* gn = g + (size_t)n * 28;
  #pragma unroll
  for (int w = 0; w < 16; ++w) { float a = 0; for (int v = 0; v < 23; ++v) a += f[v] * w1[v * 16 + w]; gn[w] = a; }
  #pragma unroll
  for (int w = 0; w < 6;  ++w) { float a = 0; for (int v = 0; v < 23; ++v) a += f[v] * w1[368 + v * 6 + w]; gn[16 + w] = a; }
  #pragma unroll
  for (int w = 0; w < 4;  ++w) { float a = 0; for (int v = 0; v < 23; ++v) a += f[v] * w1[506 + v * 4 + w]; gn[22 + w] = a; }
}

// ---------- layer 1 gather: 8 lanes per node ----------
__global__ void __launch_bounds__(256, 3)
k_gather1(const int* __restrict__ offs, const int* __restrict__ cnt,
          const int* __restrict__ srcs, const float* __restrict__ eb,
          const float* __restrict__ g, float* __restrict__ nf1) {
  int tid = blockIdx.x * 256 + threadIdx.x;
  int n = tid >> 3, sl = tid & 7;
  if (n >= NNODES) return;
  int beg = offs[n], cn = cnt[n];
  float M[54];
  #pragma unroll
  for (int i = 0; i < 54; ++i) M[i] = 0.f;
  for (int j = sl; j < cn; j += 8) {
    int p = beg + j;
    int s = srcs[p];
    const float4* bf = (const float4*)(eb + (size_t)p * 12);
    float4 bA = bf[0], bB = bf[1];
    float bb[9] = { bA.x, bA.y, bA.z, bA.w, bB.x, bB.y, bB.z, bB.w, bf[2].x };
    float G[28];
    const float4* Gf = (const float4*)(g + (size_t)s * 28);
    #pragma unroll
    for (int q = 0; q < 7; ++q) { float4 v = Gf[q]; G[4*q]=v.x; G[4*q+1]=v.y; G[4*q+2]=v.z; G[4*q+3]=v.w; }
    #pragma unroll
    for (int u = 0; u < 16; ++u) M[u] += bb[0] * G[u];
    #pragma unroll
    for (int u = 0; u < 6; ++u)
      #pragma unroll
      for (int k = 0; k < 3; ++k) M[16 + 3 * u + k] += bb[1 + k] * G[16 + u];
    #pragma unroll
    for (int u = 0; u < 4; ++u)
      #pragma unroll
      for (int K = 0; K < 5; ++K) M[34 + 5 * u + K] += bb[4 + K] * G[22 + u];
  }
  #pragma unroll
  for (int m = 1; m < 8; m <<= 1)
    #pragma unroll
    for (int i = 0; i < 54; ++i) M[i] += __shfl_xor(M[i], m);
  const float S23 = 0.20851441405707477f;
  float sc = S23 * rsqrtf((float)cn);
  float* o = nf1 + (size_t)n * 56;
  int st = sl * 7, en = (st + 7 < 54) ? st + 7 : 54;
  for (int i = st; i < en; ++i) o[i] = sc * M[i];
}

// ---------- layer 2 gather: full TP2 + TP3-precompute, 8 lanes per node ----------
__global__ void __launch_bounds__(256, 3)
k_gather2(const int* __restrict__ offs, const int* __restrict__ cnt,
          const int* __restrict__ srcs, const float* __restrict__ eb,
          const float* __restrict__ nf1, const float* __restrict__ w2,
          const float* __restrict__ w3, float* __restrict__ hh) {
  __shared__ float W[596];
  __shared__ float w3s[13];
  for (int i = threadIdx.x; i < 596; i += 256) W[i] = w2[i];
  if (threadIdx.x < 13) w3s[threadIdx.x] = w3[threadIdx.x];
  __syncthreads();
  int tid = blockIdx.x * 256 + threadIdx.x;
  int n = tid >> 3, sl = tid & 7;
  if (n >= NNODES) return;
  int beg = offs[n], cn = cnt[n];
  float O0[8], O2[9], O3[10];
  #pragma unroll
  for (int i = 0; i < 8; ++i) O0[i] = 0.f;
  #pragma unroll
  for (int i = 0; i < 9; ++i) O2[i] = 0.f;
  #pragma unroll
  for (int i = 0; i < 10; ++i) O3[i] = 0.f;

  const float I3 = 0.5773502691896258f, I5 = 0.4472135954999579f;
  const float CA = 0.18257418583505536f, CB = 0.31622776601683794f, CC = 0.3651483716701107f;
  const float P = 0.2390457218668787f, Q = 0.2070196678027063f, R = 0.1195228609334394f;

  for (int j = sl; j < cn; j += 8) {
    int p = beg + j;
    int s = srcs[p];
    const float4* bf = (const float4*)(eb + (size_t)p * 12);
    float4 bA = bf[0], bB = bf[1];
    float b[9] = { bA.x, bA.y, bA.z, bA.w, bB.x, bB.y, bB.z, bB.w, bf[2].x };
    float A[56];
    const float4* Af = (const float4*)(nf1 + (size_t)s * 56);
    #pragma unroll
    for (int q = 0; q < 14; ++q) { float4 v = Af[q]; A[4*q]=v.x; A[4*q+1]=v.y; A[4*q+2]=v.z; A[4*q+3]=v.w; }

    float CBb1_0 = CB * b[1], CBb1_1 = CB * b[2], CBb1_2 = CB * b[3];
    float CAb1_0 = CA * b[1], CAb1_2 = CA * b[3], CCb1_1 = CC * b[2];
    float c121_00 = -CA * b[6] - CB * b[8], c121_01 = CB * b[5], c121_02 = CB * b[4];
    float c121_11 = CC * b[6], c121_12 = CB * b[7], c121_22 = -CA * b[6] + CB * b[8];
    float Pb2_0 = P * b[4], Pb2_2 = P * b[6], Pb2_4 = P * b[8];
    float Qb2_0 = Q * b[4], Qb2_1 = Q * b[5], Qb2_3 = Q * b[7], Qb2_4 = Q * b[8];
    float Rb2_1 = R * b[5], Rb2_2 = R * b[6], Rb2_3 = R * b[7];

    // ---- O0 (8): paths (0,0,0), (2,1,0), (3,2,0) ----
    #pragma unroll
    for (int w = 0; w < 8; ++w) {
      float t0 = 0;
      #pragma unroll
      for (int u = 0; u < 16; ++u) t0 += A[u] * W[u * 8 + w];
      float t1 = 0;
      #pragma unroll
      for (int jj = 0; jj < 3; ++jj) {
        float s1 = 0;
        #pragma unroll
        for (int u = 0; u < 6; ++u) s1 += A[16 + 3 * u + jj] * W[316 + 8 * u + w];
        t1 += s1 * b[1 + jj];
      }
      float t2 = 0;
      #pragma unroll
      for (int J = 0; J < 5; ++J) {
        float s2 = 0;
        #pragma unroll
        for (int u = 0; u < 4; ++u) s2 += A[34 + 5 * u + J] * W[472 + 8 * u + w];
        t2 += s2 * b[4 + J];
      }
      O0[w] += b[0] * t0 + I3 * t1 + I5 * t2;
    }

    // ---- O2 (3x3): paths (0,1,2), (2,0,2), (2,2,2), (3,1,2) ----
    #pragma unroll
    for (int w = 0; w < 3; ++w) {
      float ta = 0;
      #pragma unroll
      for (int u = 0; u < 16; ++u) ta += A[u] * W[128 + 3 * u + w];
      float tb[3], tc[3], td[5];
      #pragma unroll
      for (int k = 0; k < 3; ++k) {
        tb[k] = 0; tc[k] = 0;
        #pragma unroll
        for (int u = 0; u < 6; ++u) {
          tb[k] += A[16 + 3 * u + k] * W[298 + 3 * u + w];
          tc[k] += A[16 + 3 * u + k] * W[394 + 3 * u + w];
        }
      }
      #pragma unroll
      for (int I = 0; I < 5; ++I) {
        td[I] = 0;
        #pragma unroll
        for (int u = 0; u < 4; ++u) td[I] += A[34 + 5 * u + I] * W[444 + 3 * u + w];
      }
      O2[w * 3 + 0] += I3 * (b[1] * ta + b[0] * tb[0])
                     + tc[0] * c121_00 + tc[1] * c121_01 + tc[2] * c121_02
                     + td[0] * CBb1_2 + td[1] * CBb1_1 - td[2] * CAb1_0 - td[4] * CBb1_0;
      O2[w * 3 + 1] += I3 * (b[2] * ta + b[0] * tb[1])
                     + tc[0] * c121_01 + tc[1] * c121_11 + tc[2] * c121_12
                     + td[1] * CBb1_0 + td[2] * CCb1_1 + td[3] * CBb1_2;
      O2[w * 3 + 2] += I3 * (b[3] * ta + b[0] * tb[2])
                     + tc[0] * c121_02 + tc[1] * c121_12 + tc[2] * c121_22
                     + td[0] * CBb1_0 - td[2] * CAb1_2 + td[3] * CBb1_1 + td[4] * CBb1_2;
    }

    // ---- O3 (2x5): paths (0,2,3), (3,0,3), (2,1,3), (3,2,3) ----
    #pragma unroll
    for (int w = 0; w < 2; ++w) {
      float ta = 0;
      #pragma unroll
      for (int u = 0; u < 16; ++u) ta += A[u] * W[176 + 2 * u + w];
      float tb[5], td[5], tc[3];
      #pragma unroll
      for (int K = 0; K < 5; ++K) {
        tb[K] = 0; td[K] = 0;
        #pragma unroll
        for (int u = 0; u < 4; ++u) {
          tb[K] += A[34 + 5 * u + K] * W[436 + 2 * u + w];
          td[K] += A[34 + 5 * u + K] * W[516 + 2 * u + w];
        }
      }
      #pragma unroll
      for (int i = 0; i < 3; ++i) {
        tc[i] = 0;
        #pragma unroll
        for (int u = 0; u < 6; ++u) tc[i] += A[16 + 3 * u + i] * W[382 + 2 * u + w];
      }
      O3[w * 5 + 0] += I5 * (b[4] * ta + b[0] * tb[0])
                     + tc[0] * CBb1_2 + tc[2] * CBb1_0
                     - Pb2_2 * td[0] + Qb2_3 * td[1] - Pb2_0 * td[2] + Qb2_1 * td[3];
      O3[w * 5 + 1] += I5 * (b[5] * ta + b[0] * tb[1])
                     + tc[0] * CBb1_1 + tc[1] * CBb1_0
                     + Qb2_3 * td[0] + (Rb2_2 - Qb2_4) * td[1] + Rb2_1 * td[2] + Qb2_0 * td[3] - Qb2_1 * td[4];
      O3[w * 5 + 2] += I5 * (b[6] * ta + b[0] * tb[2])
                     - tc[0] * CAb1_0 + tc[1] * CCb1_1 - tc[2] * CAb1_2
                     - Pb2_0 * td[0] + Rb2_1 * td[1] + Pb2_2 * td[2] + Rb2_3 * td[3] - Pb2_4 * td[4];
      O3[w * 5 + 3] += I5 * (b[7] * ta + b[0] * tb[3])
                     + tc[1] * CBb1_2 + tc[2] * CBb1_1
                     + Qb2_1 * td[0] + Qb2_0 * td[1] + Rb2_3 * td[2] + (Rb2_2 + Qb2_4) * td[3] + Qb2_3 * td[4];
      O3[w * 5 + 4] += I5 * (b[8] * ta + b[0] * tb[4])
                     - tc[0] * CBb1_0 + tc[2] * CBb1_2
                     - Qb2_1 * td[1] - Pb2_4 * td[2] + Qb2_3 * td[3] - Pb2_2 * td[4];
    }
  }

  // butterfly reduce across the 8 lanes (all lanes end with the full sums)
  #pragma unroll
  for (int m = 1; m < 8; m <<= 1) {
    #pragma unroll
    for (int i = 0; i < 8; ++i) O0[i] += __shfl_xor(O0[i], m);
    #pragma unroll
    for (int i = 0; i < 9; ++i) O2[i] += __shfl_xor(O2[i], m);
    #pragma unroll
    for (int i = 0; i < 10; ++i) O3[i] += __shfl_xor(O3[i], m);
  }

  const float S26 = 0.19611613513818404f, S14 = 0.2672612419124244f, S8 = 0.35355339059327373f;
  const float S13 = 0.2773500981126146f;
  float di = rsqrtf((float)cn);
  float F[27];
  #pragma unroll
  for (int w = 0; w < 8; ++w) F[w] = S26 * di * O0[w];
  #pragma unroll
  for (int i = 0; i < 9; ++i) F[8 + i] = S14 * di * O2[i];
  #pragma unroll
  for (int i = 0; i < 10; ++i) F[17 + i] = S8 * di * O3[i];

  float h[9];
  float t0 = 0;
  #pragma unroll
  for (int u = 0; u < 8; ++u) t0 += F[u] * w3s[u];
  h[0] = S13 * t0;
  #pragma unroll
  for (int jj = 0; jj < 3; ++jj) {
    float s1 = 0;
    #pragma unroll
    for (int u = 0; u < 3; ++u) s1 += F[8 + 3 * u + jj] * w3s[8 + u];
    h[1 + jj] = S13 * I3 * s1;
  }
  #pragma unroll
  for (int K = 0; K < 5; ++K)
    h[4 + K] = S13 * I5 * (F[17 + K] * w3s[11] + F[22 + K] * w3s[12]);

  float* o = hh + (size_t)n * 12;
  o[sl] = h[sl];
  if (sl == 0) o[8] = h[8];
}

// ---------- layer 3 gather + molecule reduce, 8 lanes per node ----------
__global__ void __launch_bounds__(256, 3)
k_gather3(const int* __restrict__ offs, const int* __restrict__ cnt,
          const int* __restrict__ srcs, const float* __restrict__ eb,
          const float* __restrict__ hh, const int* __restrict__ batch,
          float* __restrict__ out) {
  int tid = blockIdx.x * 256 + threadIdx.x;
  int n = tid >> 3, sl = tid & 7;
  if (n >= NNODES) return;
  int beg = offs[n], cn = cnt[n];
  float v = 0.f;
  for (int j = sl; j < cn; j += 8) {
    int p = beg + j;
    int s = srcs[p];
    const float4* bf = (const float4*)(eb + (size_t)p * 12);
    float4 bA = bf[0], bB = bf[1];
    float b8 = bf[2].x;
    const float4* Hf = (const float4*)(hh + (size_t)s * 12);
    float4 hA = Hf[0], hB = Hf[1];
    float h8 = Hf[2].x;
    v += bA.x * hA.x + bA.y * hA.y + bA.z * hA.z + bA.w * hA.w
       + bB.x * hB.x + bB.y * hB.y + bB.z * hB.z + bB.w * hB.w
       + b8 * h8;
  }
  #pragma unroll
  for (int m = 1; m < 8; m <<= 1) v += __shfl_xor(v, m);
  if (sl == 0) {
    float di = rsqrtf((float)cn);
    unsafeAtomicAdd(out + batch[n], v * di * 0.2f);  // /sqrt(apm)=/5
  }
}

extern "C" void kernel_launch(void* const* d_in, const int* in_sizes, int n_in,
                              void* d_out, int out_size, void* d_ws, size_t ws_size,
                              hipStream_t stream) {
  const float* positions = (const float*)d_in[0];
  const float* x         = (const float*)d_in[1];
  const float* edge_attr = (const float*)d_in[2];
  const float* lin_w     = (const float*)d_in[3];
  const float* lin_b     = (const float*)d_in[4];
  const float* w_tp1     = (const float*)d_in[5];
  const float* w_tp2     = (const float*)d_in[6];
  const float* w_tp3     = (const float*)d_in[7];
  const int*   edge_src  = (const int*)d_in[8];
  const int*   edge_dst  = (const int*)d_in[9];
  const int*   batch     = (const int*)d_in[10];
  float* out = (float*)d_out;

  int*   cnt  = (int*)d_ws + OFF_CNT;
  int*   offs = (int*)d_ws + OFF_OFFS;
  int*   curs = (int*)d_ws + OFF_CURS;
  int*   bsum = (int*)d_ws + OFF_BSUM;
  int*   srcs = (int*)d_ws + OFF_SRCS;
  float* eb   = (float*)d_ws + OFF_EB;
  float* g    = (float*)d_ws + OFF_G;
  float* nf1  = (float*)d_ws + OFF_NF1;
  float* hh   = (float*)d_ws + OFF_HH;

  hipMemsetAsync(cnt, 0, NNODES * sizeof(int), stream);
  hipMemsetAsync(out, 0, (size_t)out_size * sizeof(float), stream);

  dim3 blk256(256);
  dim3 gEdge((NEDGES + 255) / 256);
  dim3 gNode256((NNODES + 255) / 256);
  dim3 gCoop((NNODES * 8 + 255) / 256);

  k_count<<<gEdge, blk256, 0, stream>>>(edge_dst, cnt);
  k_scanA<<<dim3(NBLK), blk256, 0, stream>>>(cnt, offs, bsum);
  k_scanB<<<dim3(1), blk256, 0, stream>>>(bsum);
  k_scanC<<<dim3(NBLK), blk256, 0, stream>>>(offs, curs, bsum);
  k_fill<<<gEdge, blk256, 0, stream>>>(positions, edge_attr, edge_src, edge_dst, curs, srcs, eb);
  k_node1<<<gNode256, blk256, 0, stream>>>(x, lin_w, lin_b, w_tp1, g);
  k_gather1<<<gCoop, blk256, 0, stream>>>(offs, cnt, srcs, eb, g, nf1);
  k_gather2<<<gCoop, blk256, 0, stream>>>(offs, cnt, srcs, eb, nf1, w_tp2, w_tp3, hh);
  k_gather3<<<gCoop, blk256, 0, stream>>>(offs, cnt, srcs, eb, hh, batch, out);
}

// Round 5
// 326.838 us; speedup vs baseline: 4.3386x; 4.3386x over previous
//
#include <hip/hip_runtime.h>

#define NNODES 50000
#define NEDGES 400000
#define NMOLS  2000
#define NBLK   196   // ceil(NNODES/256)

// ---- ws layout (4-byte units), total 16,350,256 floats = 65.4 MB ----
constexpr size_t OFF_CNT   = 0;         // 50000 int (zeroed each call)
constexpr size_t OFF_OFFS  = 50000;     // 50000 int
constexpr size_t OFF_CURS  = 100000;    // 50000 int
constexpr size_t OFF_BSUM  = 150000;    // 256 int
constexpr size_t OFF_SRCS  = 150256;    // 400000 int (CSR-ordered src)
constexpr size_t OFF_EB    = 550256;    // 400000*12 floats (b[9]+pad, CSR order)
constexpr size_t OFF_G     = 5350256;   // 50000*28 floats (dead after k_gather1)
constexpr size_t OFF_HH    = 5350256;   // 50000*12 floats — overlays g (safe)
constexpr size_t OFF_NF1   = 6750256;   // 50000*56 floats (54 used)
constexpr size_t OFF_T     = 9550256;   // 50000*136 floats
// end: 16,350,256

__device__ __forceinline__ void make_b(float w0, float dx, float dy, float dz, float* b) {
  const float s3 = 1.7320508075688772f, s5c = 2.2360679774997896f, s15 = 3.872983346207417f;
  float r2 = dx * dx + dy * dy + dz * dz;
  b[0] = w0;
  b[1] = w0 * s3 * dy;
  b[2] = w0 * s3 * dz;
  b[3] = w0 * s3 * dx;
  b[4] = w0 * s15 * dx * dy;
  b[5] = w0 * s15 * dy * dz;
  b[6] = w0 * 0.5f * s5c * (3.f * dz * dz - r2);
  b[7] = w0 * s15 * dx * dz;
  b[8] = w0 * 0.5f * s15 * (dx * dx - dy * dy);
}

// ---------- CSR build ----------
__global__ void k_count(const int* __restrict__ dst, int* __restrict__ cnt) {
  int e = blockIdx.x * blockDim.x + threadIdx.x;
  if (e < NEDGES) atomicAdd(cnt + dst[e], 1);
}

__global__ void k_scanA(const int* __restrict__ cnt, int* __restrict__ offs, int* __restrict__ bsum) {
  __shared__ int sh[256];
  int t = threadIdx.x, i = blockIdx.x * 256 + t;
  int c = (i < NNODES) ? cnt[i] : 0;
  sh[t] = c; __syncthreads();
  #pragma unroll
  for (int off = 1; off < 256; off <<= 1) {
    int v = (t >= off) ? sh[t - off] : 0; __syncthreads();
    sh[t] += v; __syncthreads();
  }
  if (i < NNODES) offs[i] = sh[t] - c;
  if (t == 255) bsum[blockIdx.x] = sh[255];
}

__global__ void k_scanB(int* __restrict__ bsum) {
  __shared__ int sh[256];
  int t = threadIdx.x;
  int v = (t < NBLK) ? bsum[t] : 0;
  sh[t] = v; __syncthreads();
  #pragma unroll
  for (int off = 1; off < 256; off <<= 1) {
    int u = (t >= off) ? sh[t - off] : 0; __syncthreads();
    sh[t] += u; __syncthreads();
  }
  bsum[t] = sh[t] - v;
}

__global__ void k_scanC(int* __restrict__ offs, int* __restrict__ curs, const int* __restrict__ bsum) {
  int i = blockIdx.x * 256 + threadIdx.x;
  if (i < NNODES) {
    int o = offs[i] + bsum[blockIdx.x];
    offs[i] = o;
    curs[i] = o;
  }
}

__global__ void k_fill(const float* __restrict__ pos, const float* __restrict__ ea,
                       const int* __restrict__ src, const int* __restrict__ dst,
                       int* __restrict__ curs, int* __restrict__ srcs, float* __restrict__ eb) {
  int e = blockIdx.x * blockDim.x + threadIdx.x;
  if (e >= NEDGES) return;
  int s = src[e], d = dst[e];
  int p = atomicAdd(curs + d, 1);
  srcs[p] = s;
  float dx = pos[3 * s] - pos[3 * d];
  float dy = pos[3 * s + 1] - pos[3 * d + 1];
  float dz = pos[3 * s + 2] - pos[3 * d + 2];
  float b[9];
  make_b(ea[(size_t)e * 7], dx, dy, dz, b);
  float4* o = (float4*)(eb + (size_t)p * 12);
  o[0] = make_float4(b[0], b[1], b[2], b[3]);
  o[1] = make_float4(b[4], b[5], b[6], b[7]);
  o[2] = make_float4(b[8], 0.f, 0.f, 0.f);
}

// ---------- node linear + TP1 precompute ----------
__global__ void k_node1(const float* __restrict__ x, const float* __restrict__ lw,
                        const float* __restrict__ lb, const float* __restrict__ w1,
                        float* __restrict__ g) {
  int n = blockIdx.x * blockDim.x + threadIdx.x;
  if (n >= NNODES) return;
  float f[23];
  const float* xr = x + (size_t)n * 23;
  #pragma unroll
  for (int v = 0; v < 23; ++v) {
    float acc = lb[v];
    const float* wr = lw + v * 23;
    #pragma unroll
    for (int c = 0; c < 23; ++c) acc += xr[c] * wr[c];
    f[v] = fmaxf(acc, 0.f);
  }
  float* gn = g + (size_t)n * 28;
  #pragma unroll
  for (int w = 0; w < 16; ++w) { float a = 0; for (int v = 0; v < 23; ++v) a += f[v] * w1[v * 16 + w]; gn[w] = a; }
  #pragma unroll
  for (int w = 0; w < 6;  ++w) { float a = 0; for (int v = 0; v < 23; ++v) a += f[v] * w1[368 + v * 6 + w]; gn[16 + w] = a; }
  #pragma unroll
  for (int w = 0; w < 4;  ++w) { float a = 0; for (int v = 0; v < 23; ++v) a += f[v] * w1[506 + v * 4 + w]; gn[22 + w] = a; }
}

// ---------- layer 1 gather: 8 lanes per node (uncapped regs) ----------
__global__ void k_gather1(const int* __restrict__ offs, const int* __restrict__ cnt,
                          const int* __restrict__ srcs, const float* __restrict__ eb,
                          const float* __restrict__ g, float* __restrict__ nf1) {
  int tid = blockIdx.x * 256 + threadIdx.x;
  int n = tid >> 3, sl = tid & 7;
  if (n >= NNODES) return;
  int beg = offs[n], cn = cnt[n];
  float M[54];
  #pragma unroll
  for (int i = 0; i < 54; ++i) M[i] = 0.f;
  for (int j = sl; j < cn; j += 8) {
    int p = beg + j;
    int s = srcs[p];
    const float4* bf = (const float4*)(eb + (size_t)p * 12);
    float4 bA = bf[0], bB = bf[1];
    float bb[9] = { bA.x, bA.y, bA.z, bA.w, bB.x, bB.y, bB.z, bB.w, bf[2].x };
    const float* G = g + (size_t)s * 28;
    #pragma unroll
    for (int u = 0; u < 16; ++u) M[u] += bb[0] * G[u];
    #pragma unroll
    for (int u = 0; u < 6; ++u) {
      float gv = G[16 + u];
      #pragma unroll
      for (int k = 0; k < 3; ++k) M[16 + 3 * u + k] += bb[1 + k] * gv;
    }
    #pragma unroll
    for (int u = 0; u < 4; ++u) {
      float gv = G[22 + u];
      #pragma unroll
      for (int K = 0; K < 5; ++K) M[34 + 5 * u + K] += bb[4 + K] * gv;
    }
  }
  #pragma unroll
  for (int m = 1; m < 8; m <<= 1)
    #pragma unroll
    for (int i = 0; i < 54; ++i) M[i] += __shfl_xor(M[i], m);
  const float S23 = 0.20851441405707477f;
  float sc = S23 * rsqrtf((float)cn);
  float* o = nf1 + (size_t)n * 56;
  int st = sl * 7, en = (st + 7 < 54) ? st + 7 : 54;
  for (int i = st; i < en; ++i) o[i] = sc * M[i];
}

// ---------- TP2 stage A: per-node t[136] = A x W slices ----------
__global__ void k_node2t(const float* __restrict__ nf1, const float* __restrict__ w2,
                         float* __restrict__ t) {
  __shared__ float W[596];
  for (int i = threadIdx.x; i < 596; i += 256) W[i] = w2[i];
  __syncthreads();
  int n = blockIdx.x * 256 + threadIdx.x;
  if (n >= NNODES) return;
  float A[54];
  const float4* Af = (const float4*)(nf1 + (size_t)n * 56);
  #pragma unroll
  for (int q = 0; q < 13; ++q) { float4 v = Af[q]; A[4*q]=v.x; A[4*q+1]=v.y; A[4*q+2]=v.z; A[4*q+3]=v.w; }
  { float4 v = Af[13]; A[52]=v.x; A[53]=v.y; }
  float* tn = t + (size_t)n * 136;
  // A0 groups
  #pragma unroll
  for (int w = 0; w < 8; ++w) { float s = 0; for (int u = 0; u < 16; ++u) s += A[u] * W[u * 8 + w]; tn[w] = s; }
  #pragma unroll
  for (int w = 0; w < 3; ++w) { float s = 0; for (int u = 0; u < 16; ++u) s += A[u] * W[128 + 3 * u + w]; tn[8 + w] = s; }
  #pragma unroll
  for (int w = 0; w < 2; ++w) { float s = 0; for (int u = 0; u < 16; ++u) s += A[u] * W[176 + 2 * u + w]; tn[11 + w] = s; }
  // A1 groups (A[16+3u+k])
  #pragma unroll
  for (int w = 0; w < 3; ++w)
    #pragma unroll
    for (int k = 0; k < 3; ++k) { float s = 0; for (int u = 0; u < 6; ++u) s += A[16 + 3 * u + k] * W[298 + 3 * u + w]; tn[13 + 3 * w + k] = s; }
  #pragma unroll
  for (int w = 0; w < 8; ++w)
    #pragma unroll
    for (int k = 0; k < 3; ++k) { float s = 0; for (int u = 0; u < 6; ++u) s += A[16 + 3 * u + k] * W[316 + 8 * u + w]; tn[22 + 3 * w + k] = s; }
  #pragma unroll
  for (int w = 0; w < 2; ++w)
    #pragma unroll
    for (int k = 0; k < 3; ++k) { float s = 0; for (int u = 0; u < 6; ++u) s += A[16 + 3 * u + k] * W[382 + 2 * u + w]; tn[46 + 3 * w + k] = s; }
  #pragma unroll
  for (int w = 0; w < 3; ++w)
    #pragma unroll
    for (int k = 0; k < 3; ++k) { float s = 0; for (int u = 0; u < 6; ++u) s += A[16 + 3 * u + k] * W[394 + 3 * u + w]; tn[52 + 3 * w + k] = s; }
  // A2 groups (A[34+5u+K])
  #pragma unroll
  for (int w = 0; w < 2; ++w)
    #pragma unroll
    for (int K = 0; K < 5; ++K) { float s = 0; for (int u = 0; u < 4; ++u) s += A[34 + 5 * u + K] * W[436 + 2 * u + w]; tn[61 + 5 * w + K] = s; }
  #pragma unroll
  for (int w = 0; w < 3; ++w)
    #pragma unroll
    for (int K = 0; K < 5; ++K) { float s = 0; for (int u = 0; u < 4; ++u) s += A[34 + 5 * u + K] * W[444 + 3 * u + w]; tn[71 + 5 * w + K] = s; }
  #pragma unroll
  for (int w = 0; w < 8; ++w)
    #pragma unroll
    for (int K = 0; K < 5; ++K) { float s = 0; for (int u = 0; u < 4; ++u) s += A[34 + 5 * u + K] * W[472 + 8 * u + w]; tn[86 + 5 * w + K] = s; }
  #pragma unroll
  for (int w = 0; w < 2; ++w)
    #pragma unroll
    for (int K = 0; K < 5; ++K) { float s = 0; for (int u = 0; u < 4; ++u) s += A[34 + 5 * u + K] * W[516 + 2 * u + w]; tn[126 + 5 * w + K] = s; }
}

// ---------- TP2 stage B: edge combine (t consumed once per element) + TP3 precompute ----------
__global__ void k_edge2c(const int* __restrict__ offs, const int* __restrict__ cnt,
                         const int* __restrict__ srcs, const float* __restrict__ eb,
                         const float* __restrict__ t, const float* __restrict__ w3,
                         float* __restrict__ hh) {
  int tid = blockIdx.x * 256 + threadIdx.x;
  int n = tid >> 3, sl = tid & 7;
  if (n >= NNODES) return;
  int beg = offs[n], cn = cnt[n];
  float O0[8], O2[9], O3[10];
  #pragma unroll
  for (int i = 0; i < 8; ++i) O0[i] = 0.f;
  #pragma unroll
  for (int i = 0; i < 9; ++i) O2[i] = 0.f;
  #pragma unroll
  for (int i = 0; i < 10; ++i) O3[i] = 0.f;

  const float I3 = 0.5773502691896258f, I5 = 0.4472135954999579f;
  const float CA = 0.18257418583505536f, CB = 0.31622776601683794f, CC = 0.3651483716701107f;
  const float P = 0.2390457218668787f, Q = 0.2070196678027063f, R = 0.1195228609334394f;

  for (int j = sl; j < cn; j += 8) {
    int p = beg + j;
    int s = srcs[p];
    const float* T = t + (size_t)s * 136;
    const float4* bf = (const float4*)(eb + (size_t)p * 12);
    float4 bA = bf[0], bB = bf[1];
    float b[9] = { bA.x, bA.y, bA.z, bA.w, bB.x, bB.y, bB.z, bB.w, bf[2].x };

    float CBb1_0 = CB * b[1], CBb1_1 = CB * b[2], CBb1_2 = CB * b[3];
    float CAb1_0 = CA * b[1], CAb1_2 = CA * b[3], CCb1_1 = CC * b[2];
    float c121_00 = -CA * b[6] - CB * b[8], c121_01 = CB * b[5], c121_02 = CB * b[4];
    float c121_11 = CC * b[6], c121_12 = CB * b[7], c121_22 = -CA * b[6] + CB * b[8];
    float Pb2_0 = P * b[4], Pb2_2 = P * b[6], Pb2_4 = P * b[8];
    float Qb2_0 = Q * b[4], Qb2_1 = Q * b[5], Qb2_3 = Q * b[7], Qb2_4 = Q * b[8];
    float Rb2_1 = R * b[5], Rb2_2 = R * b[6], Rb2_3 = R * b[7];

    // O0 (8): t[w] + t[22..45]*b1 + t[86..125]*b2
    #pragma unroll
    for (int w = 0; w < 8; ++w) {
      O0[w] += b[0] * T[w]
             + I3 * (T[22 + 3 * w] * b[1] + T[23 + 3 * w] * b[2] + T[24 + 3 * w] * b[3])
             + I5 * (T[86 + 5 * w] * b[4] + T[87 + 5 * w] * b[5] + T[88 + 5 * w] * b[6]
                   + T[89 + 5 * w] * b[7] + T[90 + 5 * w] * b[8]);
    }
    // O2 (3x3)
    #pragma unroll
    for (int w = 0; w < 3; ++w) {
      float ta  = T[8 + w];
      float tb0 = T[13 + 3 * w], tb1 = T[14 + 3 * w], tb2 = T[15 + 3 * w];
      float tc0 = T[52 + 3 * w], tc1 = T[53 + 3 * w], tc2 = T[54 + 3 * w];
      float td0 = T[71 + 5 * w], td1 = T[72 + 5 * w], td2 = T[73 + 5 * w], td3 = T[74 + 5 * w], td4 = T[75 + 5 * w];
      O2[3 * w + 0] += I3 * (b[1] * ta + b[0] * tb0)
                     + tc0 * c121_00 + tc1 * c121_01 + tc2 * c121_02
                     + td0 * CBb1_2 + td1 * CBb1_1 - td2 * CAb1_0 - td4 * CBb1_0;
      O2[3 * w + 1] += I3 * (b[2] * ta + b[0] * tb1)
                     + tc0 * c121_01 + tc1 * c121_11 + tc2 * c121_12
                     + td1 * CBb1_0 + td2 * CCb1_1 + td3 * CBb1_2;
      O2[3 * w + 2] += I3 * (b[3] * ta + b[0] * tb2)
                     + tc0 * c121_02 + tc1 * c121_12 + tc2 * c121_22
                     + td0 * CBb1_0 - td2 * CAb1_2 + td3 * CBb1_1 + td4 * CBb1_2;
    }
    // O3 (2x5)
    #pragma unroll
    for (int w = 0; w < 2; ++w) {
      float ta  = T[11 + w];
      float tb0 = T[61 + 5 * w], tb1 = T[62 + 5 * w], tb2 = T[63 + 5 * w], tb3 = T[64 + 5 * w], tb4 = T[65 + 5 * w];
      float tc0 = T[46 + 3 * w], tc1 = T[47 + 3 * w], tc2 = T[48 + 3 * w];
      float td0 = T[126 + 5 * w], td1 = T[127 + 5 * w], td2 = T[128 + 5 * w], td3 = T[129 + 5 * w], td4 = T[130 + 5 * w];
      O3[5 * w + 0] += I5 * (b[4] * ta + b[0] * tb0)
                     + tc0 * CBb1_2 + tc2 * CBb1_0
                     - Pb2_2 * td0 + Qb2_3 * td1 - Pb2_0 * td2 + Qb2_1 * td3;
      O3[5 * w + 1] += I5 * (b[5] * ta + b[0] * tb1)
                     + tc0 * CBb1_1 + tc1 * CBb1_0
                     + Qb2_3 * td0 + (Rb2_2 - Qb2_4) * td1 + Rb2_1 * td2 + Qb2_0 * td3 - Qb2_1 * td4;
      O3[5 * w + 2] += I5 * (b[6] * ta + b[0] * tb2)
                     - tc0 * CAb1_0 + tc1 * CCb1_1 - tc2 * CAb1_2
                     - Pb2_0 * td0 + Rb2_1 * td1 + Pb2_2 * td2 + Rb2_3 * td3 - Pb2_4 * td4;
      O3[5 * w + 3] += I5 * (b[7] * ta + b[0] * tb3)
                     + tc1 * CBb1_2 + tc2 * CBb1_1
                     + Qb2_1 * td0 + Qb2_0 * td1 + Rb2_3 * td2 + (Rb2_2 + Qb2_4) * td3 + Qb2_3 * td4;
      O3[5 * w + 4] += I5 * (b[8] * ta + b[0] * tb4)
                     - tc0 * CBb1_0 + tc2 * CBb1_2
                     - Qb2_1 * td1 - Pb2_4 * td2 + Qb2_3 * td3 - Pb2_2 * td4;
    }
  }

  #pragma unroll
  for (int m = 1; m < 8; m <<= 1) {
    #pragma unroll
    for (int i = 0; i < 8; ++i) O0[i] += __shfl_xor(O0[i], m);
    #pragma unroll
    for (int i = 0; i < 9; ++i) O2[i] += __shfl_xor(O2[i], m);
    #pragma unroll
    for (int i = 0; i < 10; ++i) O3[i] += __shfl_xor(O3[i], m);
  }

  const float S26 = 0.19611613513818404f, S14 = 0.2672612419124244f, S8 = 0.35355339059327373f;
  const float S13 = 0.2773500981126146f;
  float di = rsqrtf((float)cn);
  float F[27];
  #pragma unroll
  for (int w = 0; w < 8; ++w) F[w] = S26 * di * O0[w];
  #pragma unroll
  for (int i = 0; i < 9; ++i) F[8 + i] = S14 * di * O2[i];
  #pragma unroll
  for (int i = 0; i < 10; ++i) F[17 + i] = S8 * di * O3[i];

  float h[9];
  float t0 = 0;
  #pragma unroll
  for (int u = 0; u < 8; ++u) t0 += F[u] * w3[u];
  h[0] = S13 * t0;
  #pragma unroll
  for (int jj = 0; jj < 3; ++jj) {
    float s1 = 0;
    #pragma unroll
    for (int u = 0; u < 3; ++u) s1 += F[8 + 3 * u + jj] * w3[8 + u];
    h[1 + jj] = S13 * I3 * s1;
  }
  #pragma unroll
  for (int K = 0; K < 5; ++K)
    h[4 + K] = S13 * I5 * (F[17 + K] * w3[11] + F[22 + K] * w3[12]);

  float* o = hh + (size_t)n * 12;
  o[sl] = h[sl];
  if (sl == 0) o[8] = h[8];
}

// ---------- layer 3 gather + molecule reduce ----------
__global__ void k_gather3(const int* __restrict__ offs, const int* __restrict__ cnt,
                          const int* __restrict__ srcs, const float* __restrict__ eb,
                          const float* __restrict__ hh, const int* __restrict__ batch,
                          float* __restrict__ out) {
  int tid = blockIdx.x * 256 + threadIdx.x;
  int n = tid >> 3, sl = tid & 7;
  if (n >= NNODES) return;
  int beg = offs[n], cn = cnt[n];
  float v = 0.f;
  for (int j = sl; j < cn; j += 8) {
    int p = beg + j;
    int s = srcs[p];
    const float4* bf = (const float4*)(eb + (size_t)p * 12);
    float4 bA = bf[0], bB = bf[1];
    float b8 = bf[2].x;
    const float4* Hf = (const float4*)(hh + (size_t)s * 12);
    float4 hA = Hf[0], hB = Hf[1];
    float h8 = Hf[2].x;
    v += bA.x * hA.x + bA.y * hA.y + bA.z * hA.z + bA.w * hA.w
       + bB.x * hB.x + bB.y * hB.y + bB.z * hB.z + bB.w * hB.w
       + b8 * h8;
  }
  #pragma unroll
  for (int m = 1; m < 8; m <<= 1) v += __shfl_xor(v, m);
  if (sl == 0) {
    float di = rsqrtf((float)cn);
    unsafeAtomicAdd(out + batch[n], v * di * 0.2f);  // /sqrt(apm)=/5
  }
}

extern "C" void kernel_launch(void* const* d_in, const int* in_sizes, int n_in,
                              void* d_out, int out_size, void* d_ws, size_t ws_size,
                              hipStream_t stream) {
  const float* positions = (const float*)d_in[0];
  const float* x         = (const float*)d_in[1];
  const float* edge_attr = (const float*)d_in[2];
  const float* lin_w     = (const float*)d_in[3];
  const float* lin_b     = (const float*)d_in[4];
  const float* w_tp1     = (const float*)d_in[5];
  const float* w_tp2     = (const float*)d_in[6];
  const float* w_tp3     = (const float*)d_in[7];
  const int*   edge_src  = (const int*)d_in[8];
  const int*   edge_dst  = (const int*)d_in[9];
  const int*   batch     = (const int*)d_in[10];
  float* out = (float*)d_out;

  int*   cnt  = (int*)d_ws + OFF_CNT;
  int*   offs = (int*)d_ws + OFF_OFFS;
  int*   curs = (int*)d_ws + OFF_CURS;
  int*   bsum = (int*)d_ws + OFF_BSUM;
  int*   srcs = (int*)d_ws + OFF_SRCS;
  float* eb   = (float*)d_ws + OFF_EB;
  float* g    = (float*)d_ws + OFF_G;
  float* hh   = (float*)d_ws + OFF_HH;
  float* nf1  = (float*)d_ws + OFF_NF1;
  float* t    = (float*)d_ws + OFF_T;

  hipMemsetAsync(cnt, 0, NNODES * sizeof(int), stream);
  hipMemsetAsync(out, 0, (size_t)out_size * sizeof(float), stream);

  dim3 blk256(256);
  dim3 gEdge((NEDGES + 255) / 256);
  dim3 gNode256((NNODES + 255) / 256);
  dim3 gCoop((NNODES * 8 + 255) / 256);

  k_count<<<gEdge, blk256, 0, stream>>>(edge_dst, cnt);
  k_scanA<<<dim3(NBLK), blk256, 0, stream>>>(cnt, offs, bsum);
  k_scanB<<<dim3(1), blk256, 0, stream>>>(bsum);
  k_scanC<<<dim3(NBLK), blk256, 0, stream>>>(offs, curs, bsum);
  k_fill<<<gEdge, blk256, 0, stream>>>(positions, edge_attr, edge_src, edge_dst, curs, srcs, eb);
  k_node1<<<gNode256, blk256, 0, stream>>>(x, lin_w, lin_b, w_tp1, g);
  k_gather1<<<gCoop, blk256, 0, stream>>>(offs, cnt, srcs, eb, g, nf1);
  k_node2t<<<gNode256, blk256, 0, stream>>>(nf1, w_tp2, t);
  k_edge2c<<<gCoop, blk256, 0, stream>>>(offs, cnt, srcs, eb, t, w_tp3, hh);
  k_gather3<<<gCoop, blk256, 0, stream>>>(offs, cnt, srcs, eb, hh, batch, out);
}

// Round 6
// 312.057 us; speedup vs baseline: 4.5441x; 1.0474x over previous
//
#include <hip/hip_runtime.h>

#define NNODES 50000
#define NEDGES 400000
#define NMOLS  2000
#define NBLK   196   // ceil(NNODES/256)

// ---- ws layout (4-byte units), total 10,350,256 floats = 41.4 MB ----
constexpr size_t OFF_CNT   = 0;         // 50000 int (zeroed each call)
constexpr size_t OFF_OFFS  = 50000;     // 50000 int
constexpr size_t OFF_CURS  = 100000;    // 50000 int
constexpr size_t OFF_BSUM  = 150000;    // 256 int
constexpr size_t OFF_SRCS  = 150256;    // 400000 int (CSR-ordered src)
constexpr size_t OFF_EB4   = 550256;    // 400000*4 floats (dx,dy,dz,w0), 16B rows
constexpr size_t OFF_GB    = 2150256;   // 50000*16 uints (26 bf16 + pad = 64B rows)
constexpr size_t OFF_NF1   = 2950256;   // 50000*56 floats (54 used)
constexpr size_t OFF_TB    = 5750256;   // 50000*80 uints (144 bf16 + pad, 320B rows)
constexpr size_t OFF_HH    = 9750256;   // 50000*12 floats (9 used)
// end: 10,350,256

__device__ __forceinline__ unsigned short f2bf(float f) {
  unsigned int b = __float_as_uint(f);
  unsigned int r = (b + 0x7FFFu + ((b >> 16) & 1u)) >> 16;  // RNE
  return (unsigned short)r;
}
__device__ __forceinline__ float bflo(unsigned int u) { return __uint_as_float(u << 16); }
__device__ __forceinline__ float bfhi(unsigned int u) { return __uint_as_float(u & 0xFFFF0000u); }
__device__ __forceinline__ unsigned int packbf(float a, float b) {
  return (unsigned int)f2bf(a) | ((unsigned int)f2bf(b) << 16);
}

__device__ __forceinline__ void make_b(float w0, float dx, float dy, float dz, float* b) {
  const float s3 = 1.7320508075688772f, s5c = 2.2360679774997896f, s15 = 3.872983346207417f;
  float r2 = dx * dx + dy * dy + dz * dz;
  b[0] = w0;
  b[1] = w0 * s3 * dy;
  b[2] = w0 * s3 * dz;
  b[3] = w0 * s3 * dx;
  b[4] = w0 * s15 * dx * dy;
  b[5] = w0 * s15 * dy * dz;
  b[6] = w0 * 0.5f * s5c * (3.f * dz * dz - r2);
  b[7] = w0 * s15 * dx * dz;
  b[8] = w0 * 0.5f * s15 * (dx * dx - dy * dy);
}

// ---------- CSR build ----------
__global__ void k_count(const int* __restrict__ dst, int* __restrict__ cnt) {
  int e = blockIdx.x * blockDim.x + threadIdx.x;
  if (e < NEDGES) atomicAdd(cnt + dst[e], 1);
}

__global__ void k_scanA(const int* __restrict__ cnt, int* __restrict__ offs, int* __restrict__ bsum) {
  __shared__ int sh[256];
  int t = threadIdx.x, i = blockIdx.x * 256 + t;
  int c = (i < NNODES) ? cnt[i] : 0;
  sh[t] = c; __syncthreads();
  #pragma unroll
  for (int off = 1; off < 256; off <<= 1) {
    int v = (t >= off) ? sh[t - off] : 0; __syncthreads();
    sh[t] += v; __syncthreads();
  }
  if (i < NNODES) offs[i] = sh[t] - c;
  if (t == 255) bsum[blockIdx.x] = sh[255];
}

__global__ void k_scanB(int* __restrict__ bsum) {
  __shared__ int sh[256];
  int t = threadIdx.x;
  int v = (t < NBLK) ? bsum[t] : 0;
  sh[t] = v; __syncthreads();
  #pragma unroll
  for (int off = 1; off < 256; off <<= 1) {
    int u = (t >= off) ? sh[t - off] : 0; __syncthreads();
    sh[t] += u; __syncthreads();
  }
  bsum[t] = sh[t] - v;
}

__global__ void k_scanC(int* __restrict__ offs, int* __restrict__ curs, const int* __restrict__ bsum) {
  int i = blockIdx.x * 256 + threadIdx.x;
  if (i < NNODES) {
    int o = offs[i] + bsum[blockIdx.x];
    offs[i] = o;
    curs[i] = o;
  }
}

__global__ void k_fill(const float* __restrict__ pos, const float* __restrict__ ea,
                       const int* __restrict__ src, const int* __restrict__ dst,
                       int* __restrict__ curs, int* __restrict__ srcs, float4* __restrict__ eb4) {
  int e = blockIdx.x * blockDim.x + threadIdx.x;
  if (e >= NEDGES) return;
  int s = src[e], d = dst[e];
  int p = atomicAdd(curs + d, 1);
  srcs[p] = s;
  float dx = pos[3 * s] - pos[3 * d];
  float dy = pos[3 * s + 1] - pos[3 * d + 1];
  float dz = pos[3 * s + 2] - pos[3 * d + 2];
  eb4[p] = make_float4(dx, dy, dz, ea[(size_t)e * 7]);
}

// ---------- node linear + TP1 precompute (bf16-packed g, one 64B line/row) ----------
__global__ void k_node1(const float* __restrict__ x, const float* __restrict__ lw,
                        const float* __restrict__ lb, const float* __restrict__ w1,
                        unsigned int* __restrict__ gb) {
  int n = blockIdx.x * blockDim.x + threadIdx.x;
  if (n >= NNODES) return;
  float f[23];
  const float* xr = x + (size_t)n * 23;
  #pragma unroll
  for (int v = 0; v < 23; ++v) {
    float acc = lb[v];
    const float* wr = lw + v * 23;
    #pragma unroll
    for (int c = 0; c < 23; ++c) acc += xr[c] * wr[c];
    f[v] = fmaxf(acc, 0.f);
  }
  float G[26];
  #pragma unroll
  for (int w = 0; w < 16; ++w) { float a = 0; for (int v = 0; v < 23; ++v) a += f[v] * w1[v * 16 + w]; G[w] = a; }
  #pragma unroll
  for (int w = 0; w < 6;  ++w) { float a = 0; for (int v = 0; v < 23; ++v) a += f[v] * w1[368 + v * 6 + w]; G[16 + w] = a; }
  #pragma unroll
  for (int w = 0; w < 4;  ++w) { float a = 0; for (int v = 0; v < 23; ++v) a += f[v] * w1[506 + v * 4 + w]; G[22 + w] = a; }
  unsigned int U[16];
  #pragma unroll
  for (int i = 0; i < 13; ++i) U[i] = packbf(G[2 * i], G[2 * i + 1]);
  U[13] = U[14] = U[15] = 0u;
  uint4* o = (uint4*)(gb + (size_t)n * 16);
  o[0] = make_uint4(U[0], U[1], U[2], U[3]);
  o[1] = make_uint4(U[4], U[5], U[6], U[7]);
  o[2] = make_uint4(U[8], U[9], U[10], U[11]);
  o[3] = make_uint4(U[12], U[13], U[14], U[15]);
}

// ---------- layer 1 gather: 8 lanes per node ----------
__global__ void k_gather1(const int* __restrict__ offs, const int* __restrict__ cnt,
                          const int* __restrict__ srcs, const float4* __restrict__ eb4,
                          const unsigned int* __restrict__ gb, float* __restrict__ nf1) {
  int tid = blockIdx.x * 256 + threadIdx.x;
  int n = tid >> 3, sl = tid & 7;
  if (n >= NNODES) return;
  int beg = offs[n], cn = cnt[n];
  float M[54];
  #pragma unroll
  for (int i = 0; i < 54; ++i) M[i] = 0.f;
  for (int j = sl; j < cn; j += 8) {
    int p = beg + j;
    int s = srcs[p];
    float4 ebv = eb4[p];
    float bb[9]; make_b(ebv.w, ebv.x, ebv.y, ebv.z, bb);
    const uint4* Gf = (const uint4*)(gb + (size_t)s * 16);
    uint4 u0 = Gf[0], u1 = Gf[1], u2 = Gf[2], u3 = Gf[3];
    unsigned int U[13] = { u0.x, u0.y, u0.z, u0.w, u1.x, u1.y, u1.z, u1.w,
                           u2.x, u2.y, u2.z, u2.w, u3.x };
    float G[26];
    #pragma unroll
    for (int i = 0; i < 13; ++i) { G[2 * i] = bflo(U[i]); G[2 * i + 1] = bfhi(U[i]); }
    #pragma unroll
    for (int u = 0; u < 16; ++u) M[u] += bb[0] * G[u];
    #pragma unroll
    for (int u = 0; u < 6; ++u) {
      float gv = G[16 + u];
      #pragma unroll
      for (int k = 0; k < 3; ++k) M[16 + 3 * u + k] += bb[1 + k] * gv;
    }
    #pragma unroll
    for (int u = 0; u < 4; ++u) {
      float gv = G[22 + u];
      #pragma unroll
      for (int K = 0; K < 5; ++K) M[34 + 5 * u + K] += bb[4 + K] * gv;
    }
  }
  #pragma unroll
  for (int m = 1; m < 8; m <<= 1)
    #pragma unroll
    for (int i = 0; i < 54; ++i) M[i] += __shfl_xor(M[i], m);
  const float S23 = 0.20851441405707477f;
  float sc = S23 * rsqrtf((float)cn);
  float* o = nf1 + (size_t)n * 56;
  int st = sl * 7, en = (st + 7 < 54) ? st + 7 : 54;
  for (int i = st; i < en; ++i) o[i] = sc * M[i];
}

// ---------- TP2 stage A: per-node t, bf16-packed in consumption order ----------
// row layout (ushort idx): O0 groups w=0..7 @10w: [s0, p2*3, q3*5, pad]
//                          O2 groups w=0..2 @80+12w: [s1, p1*3, p4*3, q2*5]
//                          O3 groups w=0..1 @116+14w: [s2, q1*5, p3*3, q4*5]
__global__ void k_node2t(const float* __restrict__ nf1, const float* __restrict__ w2,
                         unsigned int* __restrict__ tb) {
  __shared__ float W[596];
  for (int i = threadIdx.x; i < 596; i += 256) W[i] = w2[i];
  __syncthreads();
  int n = blockIdx.x * 256 + threadIdx.x;
  if (n >= NNODES) return;
  float A[54];
  const float4* Af = (const float4*)(nf1 + (size_t)n * 56);
  #pragma unroll
  for (int q = 0; q < 13; ++q) { float4 v = Af[q]; A[4*q]=v.x; A[4*q+1]=v.y; A[4*q+2]=v.z; A[4*q+3]=v.w; }
  { float4 v = Af[13]; A[52]=v.x; A[53]=v.y; }

  unsigned int U[72];
  // O0 groups
  #pragma unroll
  for (int w = 0; w < 8; ++w) {
    float s0 = 0;
    #pragma unroll
    for (int u = 0; u < 16; ++u) s0 += A[u] * W[u * 8 + w];
    float p2[3];
    #pragma unroll
    for (int k = 0; k < 3; ++k) { float s = 0; for (int u = 0; u < 6; ++u) s += A[16 + 3 * u + k] * W[316 + 8 * u + w]; p2[k] = s; }
    float q3[5];
    #pragma unroll
    for (int K = 0; K < 5; ++K) { float s = 0; for (int u = 0; u < 4; ++u) s += A[34 + 5 * u + K] * W[472 + 8 * u + w]; q3[K] = s; }
    U[5 * w + 0] = packbf(s0, p2[0]);
    U[5 * w + 1] = packbf(p2[1], p2[2]);
    U[5 * w + 2] = packbf(q3[0], q3[1]);
    U[5 * w + 3] = packbf(q3[2], q3[3]);
    U[5 * w + 4] = packbf(q3[4], 0.f);
  }
  // O2 groups
  #pragma unroll
  for (int w = 0; w < 3; ++w) {
    float s1 = 0;
    #pragma unroll
    for (int u = 0; u < 16; ++u) s1 += A[u] * W[128 + 3 * u + w];
    float p1[3], p4[3];
    #pragma unroll
    for (int k = 0; k < 3; ++k) {
      float a = 0, c = 0;
      #pragma unroll
      for (int u = 0; u < 6; ++u) {
        a += A[16 + 3 * u + k] * W[298 + 3 * u + w];
        c += A[16 + 3 * u + k] * W[394 + 3 * u + w];
      }
      p1[k] = a; p4[k] = c;
    }
    float q2[5];
    #pragma unroll
    for (int K = 0; K < 5; ++K) { float s = 0; for (int u = 0; u < 4; ++u) s += A[34 + 5 * u + K] * W[444 + 3 * u + w]; q2[K] = s; }
    int base = 40 + 6 * w;
    U[base + 0] = packbf(s1, p1[0]);
    U[base + 1] = packbf(p1[1], p1[2]);
    U[base + 2] = packbf(p4[0], p4[1]);
    U[base + 3] = packbf(p4[2], q2[0]);
    U[base + 4] = packbf(q2[1], q2[2]);
    U[base + 5] = packbf(q2[3], q2[4]);
  }
  // O3 groups
  #pragma unroll
  for (int w = 0; w < 2; ++w) {
    float s2 = 0;
    #pragma unroll
    for (int u = 0; u < 16; ++u) s2 += A[u] * W[176 + 2 * u + w];
    float q1[5], q4[5];
    #pragma unroll
    for (int K = 0; K < 5; ++K) {
      float a = 0, c = 0;
      #pragma unroll
      for (int u = 0; u < 4; ++u) {
        a += A[34 + 5 * u + K] * W[436 + 2 * u + w];
        c += A[34 + 5 * u + K] * W[516 + 2 * u + w];
      }
      q1[K] = a; q4[K] = c;
    }
    float p3[3];
    #pragma unroll
    for (int k = 0; k < 3; ++k) { float s = 0; for (int u = 0; u < 6; ++u) s += A[16 + 3 * u + k] * W[382 + 2 * u + w]; p3[k] = s; }
    int base = 58 + 7 * w;
    U[base + 0] = packbf(s2, q1[0]);
    U[base + 1] = packbf(q1[1], q1[2]);
    U[base + 2] = packbf(q1[3], q1[4]);
    U[base + 3] = packbf(p3[0], p3[1]);
    U[base + 4] = packbf(p3[2], q4[0]);
    U[base + 5] = packbf(q4[1], q4[2]);
    U[base + 6] = packbf(q4[3], q4[4]);
  }
  uint4* o = (uint4*)(tb + (size_t)n * 80);
  #pragma unroll
  for (int q = 0; q < 18; ++q)
    o[q] = make_uint4(U[4 * q], U[4 * q + 1], U[4 * q + 2], U[4 * q + 3]);
}

// ---------- TP2 stage B: edge combine + TP3 precompute ----------
__global__ void k_edge2c(const int* __restrict__ offs, const int* __restrict__ cnt,
                         const int* __restrict__ srcs, const float4* __restrict__ eb4,
                         const unsigned int* __restrict__ tb, const float* __restrict__ w3,
                         float* __restrict__ hh) {
  int tid = blockIdx.x * 256 + threadIdx.x;
  int n = tid >> 3, sl = tid & 7;
  if (n >= NNODES) return;
  int beg = offs[n], cn = cnt[n];
  float O0[8], O2[9], O3[10];
  #pragma unroll
  for (int i = 0; i < 8; ++i) O0[i] = 0.f;
  #pragma unroll
  for (int i = 0; i < 9; ++i) O2[i] = 0.f;
  #pragma unroll
  for (int i = 0; i < 10; ++i) O3[i] = 0.f;

  const float I3 = 0.5773502691896258f, I5 = 0.4472135954999579f;
  const float CA = 0.18257418583505536f, CB = 0.31622776601683794f, CC = 0.3651483716701107f;
  const float P = 0.2390457218668787f, Q = 0.2070196678027063f, R = 0.1195228609334394f;

  for (int j = sl; j < cn; j += 8) {
    int p = beg + j;
    int s = srcs[p];
    const unsigned int* T = tb + (size_t)s * 80;
    float4 ebv = eb4[p];
    float b[9]; make_b(ebv.w, ebv.x, ebv.y, ebv.z, b);

    float CBb1_0 = CB * b[1], CBb1_1 = CB * b[2], CBb1_2 = CB * b[3];
    float CAb1_0 = CA * b[1], CAb1_2 = CA * b[3], CCb1_1 = CC * b[2];
    float c121_00 = -CA * b[6] - CB * b[8], c121_01 = CB * b[5], c121_02 = CB * b[4];
    float c121_11 = CC * b[6], c121_12 = CB * b[7], c121_22 = -CA * b[6] + CB * b[8];
    float Pb2_0 = P * b[4], Pb2_2 = P * b[6], Pb2_4 = P * b[8];
    float Qb2_0 = Q * b[4], Qb2_1 = Q * b[5], Qb2_3 = Q * b[7], Qb2_4 = Q * b[8];
    float Rb2_1 = R * b[5], Rb2_2 = R * b[6], Rb2_3 = R * b[7];

    // O0 (8 groups of 5 uints)
    #pragma unroll
    for (int w = 0; w < 8; ++w) {
      unsigned int u0 = T[5 * w], u1 = T[5 * w + 1], u2 = T[5 * w + 2], u3 = T[5 * w + 3], u4 = T[5 * w + 4];
      O0[w] += b[0] * bflo(u0)
             + I3 * (bfhi(u0) * b[1] + bflo(u1) * b[2] + bfhi(u1) * b[3])
             + I5 * (bflo(u2) * b[4] + bfhi(u2) * b[5] + bflo(u3) * b[6]
                   + bfhi(u3) * b[7] + bflo(u4) * b[8]);
    }
    // O2 (3 groups of 6 uints)
    #pragma unroll
    for (int w = 0; w < 3; ++w) {
      const unsigned int* Tg = T + 40 + 6 * w;
      unsigned int u0 = Tg[0], u1 = Tg[1], u2 = Tg[2], u3 = Tg[3], u4 = Tg[4], u5 = Tg[5];
      float ta  = bflo(u0);
      float tb0 = bfhi(u0), tb1 = bflo(u1), tb2 = bfhi(u1);
      float tc0 = bflo(u2), tc1 = bfhi(u2), tc2 = bflo(u3);
      float td0 = bfhi(u3), td1 = bflo(u4), td2 = bfhi(u4), td3 = bflo(u5), td4 = bfhi(u5);
      O2[3 * w + 0] += I3 * (b[1] * ta + b[0] * tb0)
                     + tc0 * c121_00 + tc1 * c121_01 + tc2 * c121_02
                     + td0 * CBb1_2 + td1 * CBb1_1 - td2 * CAb1_0 - td4 * CBb1_0;
      O2[3 * w + 1] += I3 * (b[2] * ta + b[0] * tb1)
                     + tc0 * c121_01 + tc1 * c121_11 + tc2 * c121_12
                     + td1 * CBb1_0 + td2 * CCb1_1 + td3 * CBb1_2;
      O2[3 * w + 2] += I3 * (b[3] * ta + b[0] * tb2)
                     + tc0 * c121_02 + tc1 * c121_12 + tc2 * c121_22
                     + td0 * CBb1_0 - td2 * CAb1_2 + td3 * CBb1_1 + td4 * CBb1_2;
    }
    // O3 (2 groups of 7 uints)
    #pragma unroll
    for (int w = 0; w < 2; ++w) {
      const unsigned int* Tg = T + 58 + 7 * w;
      unsigned int u0 = Tg[0], u1 = Tg[1], u2 = Tg[2], u3 = Tg[3], u4 = Tg[4], u5 = Tg[5], u6 = Tg[6];
      float ta  = bflo(u0);
      float tb0 = bfhi(u0), tb1 = bflo(u1), tb2 = bfhi(u1), tb3 = bflo(u2), tb4 = bfhi(u2);
      float tc0 = bflo(u3), tc1 = bfhi(u3), tc2 = bflo(u4);
      float td0 = bfhi(u4), td1 = bflo(u5), td2 = bfhi(u5), td3 = bflo(u6), td4 = bfhi(u6);
      O3[5 * w + 0] += I5 * (b[4] * ta + b[0] * tb0)
                     + tc0 * CBb1_2 + tc2 * CBb1_0
                     - Pb2_2 * td0 + Qb2_3 * td1 - Pb2_0 * td2 + Qb2_1 * td3;
      O3[5 * w + 1] += I5 * (b[5] * ta + b[0] * tb1)
                     + tc0 * CBb1_1 + tc1 * CBb1_0
                     + Qb2_3 * td0 + (Rb2_2 - Qb2_4) * td1 + Rb2_1 * td2 + Qb2_0 * td3 - Qb2_1 * td4;
      O3[5 * w + 2] += I5 * (b[6] * ta + b[0] * tb2)
                     - tc0 * CAb1_0 + tc1 * CCb1_1 - tc2 * CAb1_2
                     - Pb2_0 * td0 + Rb2_1 * td1 + Pb2_2 * td2 + Rb2_3 * td3 - Pb2_4 * td4;
      O3[5 * w + 3] += I5 * (b[7] * ta + b[0] * tb3)
                     + tc1 * CBb1_2 + tc2 * CBb1_1
                     + Qb2_1 * td0 + Qb2_0 * td1 + Rb2_3 * td2 + (Rb2_2 + Qb2_4) * td3 + Qb2_3 * td4;
      O3[5 * w + 4] += I5 * (b[8] * ta + b[0] * tb4)
                     - tc0 * CBb1_0 + tc2 * CBb1_2
                     - Qb2_1 * td1 - Pb2_4 * td2 + Qb2_3 * td3 - Pb2_2 * td4;
    }
  }

  #pragma unroll
  for (int m = 1; m < 8; m <<= 1) {
    #pragma unroll
    for (int i = 0; i < 8; ++i) O0[i] += __shfl_xor(O0[i], m);
    #pragma unroll
    for (int i = 0; i < 9; ++i) O2[i] += __shfl_xor(O2[i], m);
    #pragma unroll
    for (int i = 0; i < 10; ++i) O3[i] += __shfl_xor(O3[i], m);
  }

  const float S26 = 0.19611613513818404f, S14 = 0.2672612419124244f, S8 = 0.35355339059327373f;
  const float S13 = 0.2773500981126146f;
  float di = rsqrtf((float)cn);
  float F[27];
  #pragma unroll
  for (int w = 0; w < 8; ++w) F[w] = S26 * di * O0[w];
  #pragma unroll
  for (int i = 0; i < 9; ++i) F[8 + i] = S14 * di * O2[i];
  #pragma unroll
  for (int i = 0; i < 10; ++i) F[17 + i] = S8 * di * O3[i];

  float h[9];
  float t0 = 0;
  #pragma unroll
  for (int u = 0; u < 8; ++u) t0 += F[u] * w3[u];
  h[0] = S13 * t0;
  #pragma unroll
  for (int jj = 0; jj < 3; ++jj) {
    float s1 = 0;
    #pragma unroll
    for (int u = 0; u < 3; ++u) s1 += F[8 + 3 * u + jj] * w3[8 + u];
    h[1 + jj] = S13 * I3 * s1;
  }
  #pragma unroll
  for (int K = 0; K < 5; ++K)
    h[4 + K] = S13 * I5 * (F[17 + K] * w3[11] + F[22 + K] * w3[12]);

  float* o = hh + (size_t)n * 12;
  o[sl] = h[sl];
  if (sl == 0) o[8] = h[8];
}

// ---------- layer 3 gather + molecule reduce ----------
__global__ void k_gather3(const int* __restrict__ offs, const int* __restrict__ cnt,
                          const int* __restrict__ srcs, const float4* __restrict__ eb4,
                          const float* __restrict__ hh, const int* __restrict__ batch,
                          float* __restrict__ out) {
  int tid = blockIdx.x * 256 + threadIdx.x;
  int n = tid >> 3, sl = tid & 7;
  if (n >= NNODES) return;
  int beg = offs[n], cn = cnt[n];
  float v = 0.f;
  for (int j = sl; j < cn; j += 8) {
    int p = beg + j;
    int s = srcs[p];
    float4 ebv = eb4[p];
    float b[9]; make_b(ebv.w, ebv.x, ebv.y, ebv.z, b);
    const float4* Hf = (const float4*)(hh + (size_t)s * 12);
    float4 hA = Hf[0], hB = Hf[1];
    float h8 = Hf[2].x;
    v += b[0] * hA.x + b[1] * hA.y + b[2] * hA.z + b[3] * hA.w
       + b[4] * hB.x + b[5] * hB.y + b[6] * hB.z + b[7] * hB.w
       + b[8] * h8;
  }
  #pragma unroll
  for (int m = 1; m < 8; m <<= 1) v += __shfl_xor(v, m);
  if (sl == 0) {
    float di = rsqrtf((float)cn);
    unsafeAtomicAdd(out + batch[n], v * di * 0.2f);  // /sqrt(apm)=/5
  }
}

extern "C" void kernel_launch(void* const* d_in, const int* in_sizes, int n_in,
                              void* d_out, int out_size, void* d_ws, size_t ws_size,
                              hipStream_t stream) {
  const float* positions = (const float*)d_in[0];
  const float* x         = (const float*)d_in[1];
  const float* edge_attr = (const float*)d_in[2];
  const float* lin_w     = (const float*)d_in[3];
  const float* lin_b     = (const float*)d_in[4];
  const float* w_tp1     = (const float*)d_in[5];
  const float* w_tp2     = (const float*)d_in[6];
  const float* w_tp3     = (const float*)d_in[7];
  const int*   edge_src  = (const int*)d_in[8];
  const int*   edge_dst  = (const int*)d_in[9];
  const int*   batch     = (const int*)d_in[10];
  float* out = (float*)d_out;

  int*   cnt  = (int*)d_ws + OFF_CNT;
  int*   offs = (int*)d_ws + OFF_OFFS;
  int*   curs = (int*)d_ws + OFF_CURS;
  int*   bsum = (int*)d_ws + OFF_BSUM;
  int*   srcs = (int*)d_ws + OFF_SRCS;
  float4* eb4 = (float4*)((float*)d_ws + OFF_EB4);
  unsigned int* gb = (unsigned int*)((float*)d_ws + OFF_GB);
  float* nf1  = (float*)d_ws + OFF_NF1;
  unsigned int* tb = (unsigned int*)((float*)d_ws + OFF_TB);
  float* hh   = (float*)d_ws + OFF_HH;

  hipMemsetAsync(cnt, 0, NNODES * sizeof(int), stream);
  hipMemsetAsync(out, 0, (size_t)out_size * sizeof(float), stream);

  dim3 blk256(256);
  dim3 gEdge((NEDGES + 255) / 256);
  dim3 gNode256((NNODES + 255) / 256);
  dim3 gCoop((NNODES * 8 + 255) / 256);

  k_count<<<gEdge, blk256, 0, stream>>>(edge_dst, cnt);
  k_scanA<<<dim3(NBLK), blk256, 0, stream>>>(cnt, offs, bsum);
  k_scanB<<<dim3(1), blk256, 0, stream>>>(bsum);
  k_scanC<<<dim3(NBLK), blk256, 0, stream>>>(offs, curs, bsum);
  k_fill<<<gEdge, blk256, 0, stream>>>(positions, edge_attr, edge_src, edge_dst, curs, srcs, eb4);
  k_node1<<<gNode256, blk256, 0, stream>>>(x, lin_w, lin_b, w_tp1, gb);
  k_gather1<<<gCoop, blk256, 0, stream>>>(offs, cnt, srcs, eb4, gb, nf1);
  k_node2t<<<gNode256, blk256, 0, stream>>>(nf1, w_tp2, tb);
  k_edge2c<<<gCoop, blk256, 0, stream>>>(offs, cnt, srcs, eb4, tb, w_tp3, hh);
  k_gather3<<<gCoop, blk256, 0, stream>>>(offs, cnt, srcs, eb4, hh, batch, out);
}

// Round 7
// 251.057 us; speedup vs baseline: 5.6481x; 1.2430x over previous
//
#include <hip/hip_runtime.h>

#define NNODES 50000
#define NEDGES 400000
#define NMOLS  2000
#define NBLK   196   // ceil(NNODES/256)

// ---- ws layout (4-byte units), total 10,550,256 * 4B = 42.2 MB ----
constexpr size_t OFF_CNT   = 0;         // 50000 int (zeroed each call)
constexpr size_t OFF_OFFS  = 50000;     // 50000 int
constexpr size_t OFF_CURS  = 100000;    // 50000 int
constexpr size_t OFF_BSUM  = 150000;    // 256 int
constexpr size_t OFF_SRCS  = 150256;    // 400000 int (CSR-ordered src)
constexpr size_t OFF_EB4   = 550256;    // 400000*4 floats (dx,dy,dz,w0), 16B rows
constexpr size_t OFF_GB    = 2150256;   // 50000*16 uints (26 bf16 + pad = 64B rows)
constexpr size_t OFF_NF1   = 2950256;   // 50000*56 floats (54 used)
constexpr size_t OFF_TB    = 5750256;   // 50000*80 uints (144 bf16 packed, 320B rows)
constexpr size_t OFF_HH    = 9750256;   // 50000*16 floats (9 used, 64B rows)
// end: 10,550,256

__device__ __forceinline__ unsigned short f2bf(float f) {
  unsigned int b = __float_as_uint(f);
  unsigned int r = (b + 0x7FFFu + ((b >> 16) & 1u)) >> 16;  // RNE
  return (unsigned short)r;
}
__device__ __forceinline__ float bflo(unsigned int u) { return __uint_as_float(u << 16); }
__device__ __forceinline__ float bfhi(unsigned int u) { return __uint_as_float(u & 0xFFFF0000u); }
__device__ __forceinline__ unsigned int packbf(float a, float b) {
  return (unsigned int)f2bf(a) | ((unsigned int)f2bf(b) << 16);
}

__device__ __forceinline__ void make_b(float w0, float dx, float dy, float dz, float* b) {
  const float s3 = 1.7320508075688772f, s5c = 2.2360679774997896f, s15 = 3.872983346207417f;
  float r2 = dx * dx + dy * dy + dz * dz;
  b[0] = w0;
  b[1] = w0 * s3 * dy;
  b[2] = w0 * s3 * dz;
  b[3] = w0 * s3 * dx;
  b[4] = w0 * s15 * dx * dy;
  b[5] = w0 * s15 * dy * dz;
  b[6] = w0 * 0.5f * s5c * (3.f * dz * dz - r2);
  b[7] = w0 * s15 * dx * dz;
  b[8] = w0 * 0.5f * s15 * (dx * dx - dy * dy);
}

// ---------- CSR build ----------
__global__ void k_count(const int* __restrict__ dst, int* __restrict__ cnt) {
  int e = blockIdx.x * blockDim.x + threadIdx.x;
  if (e < NEDGES) atomicAdd(cnt + dst[e], 1);
}

__global__ void k_scanA(const int* __restrict__ cnt, int* __restrict__ offs, int* __restrict__ bsum) {
  __shared__ int sh[256];
  int t = threadIdx.x, i = blockIdx.x * 256 + t;
  int c = (i < NNODES) ? cnt[i] : 0;
  sh[t] = c; __syncthreads();
  #pragma unroll
  for (int off = 1; off < 256; off <<= 1) {
    int v = (t >= off) ? sh[t - off] : 0; __syncthreads();
    sh[t] += v; __syncthreads();
  }
  if (i < NNODES) offs[i] = sh[t] - c;
  if (t == 255) bsum[blockIdx.x] = sh[255];
}

__global__ void k_scanB(int* __restrict__ bsum) {
  __shared__ int sh[256];
  int t = threadIdx.x;
  int v = (t < NBLK) ? bsum[t] : 0;
  sh[t] = v; __syncthreads();
  #pragma unroll
  for (int off = 1; off < 256; off <<= 1) {
    int u = (t >= off) ? sh[t - off] : 0; __syncthreads();
    sh[t] += u; __syncthreads();
  }
  bsum[t] = sh[t] - v;
}

__global__ void k_scanC(int* __restrict__ offs, int* __restrict__ curs, const int* __restrict__ bsum) {
  int i = blockIdx.x * 256 + threadIdx.x;
  if (i < NNODES) {
    int o = offs[i] + bsum[blockIdx.x];
    offs[i] = o;
    curs[i] = o;
  }
}

__global__ void k_fill(const float* __restrict__ pos, const float* __restrict__ ea,
                       const int* __restrict__ src, const int* __restrict__ dst,
                       int* __restrict__ curs, int* __restrict__ srcs, float4* __restrict__ eb4) {
  int e = blockIdx.x * blockDim.x + threadIdx.x;
  if (e >= NEDGES) return;
  int s = src[e], d = dst[e];
  int p = atomicAdd(curs + d, 1);
  srcs[p] = s;
  float dx = pos[3 * s] - pos[3 * d];
  float dy = pos[3 * s + 1] - pos[3 * d + 1];
  float dz = pos[3 * s + 2] - pos[3 * d + 2];
  eb4[p] = make_float4(dx, dy, dz, ea[(size_t)e * 7]);
}

// ---------- node linear + TP1 precompute (bf16-packed g, one 64B line/row) ----------
__global__ void k_node1(const float* __restrict__ x, const float* __restrict__ lw,
                        const float* __restrict__ lb, const float* __restrict__ w1,
                        unsigned int* __restrict__ gb) {
  int n = blockIdx.x * blockDim.x + threadIdx.x;
  if (n >= NNODES) return;
  float f[23];
  const float* xr = x + (size_t)n * 23;
  #pragma unroll
  for (int v = 0; v < 23; ++v) {
    float acc = lb[v];
    const float* wr = lw + v * 23;
    #pragma unroll
    for (int c = 0; c < 23; ++c) acc += xr[c] * wr[c];
    f[v] = fmaxf(acc, 0.f);
  }
  float G[26];
  #pragma unroll
  for (int w = 0; w < 16; ++w) { float a = 0; for (int v = 0; v < 23; ++v) a += f[v] * w1[v * 16 + w]; G[w] = a; }
  #pragma unroll
  for (int w = 0; w < 6;  ++w) { float a = 0; for (int v = 0; v < 23; ++v) a += f[v] * w1[368 + v * 6 + w]; G[16 + w] = a; }
  #pragma unroll
  for (int w = 0; w < 4;  ++w) { float a = 0; for (int v = 0; v < 23; ++v) a += f[v] * w1[506 + v * 4 + w]; G[22 + w] = a; }
  unsigned int U[16];
  #pragma unroll
  for (int i = 0; i < 13; ++i) U[i] = packbf(G[2 * i], G[2 * i + 1]);
  U[13] = U[14] = U[15] = 0u;
  uint4* o = (uint4*)(gb + (size_t)n * 16);
  o[0] = make_uint4(U[0], U[1], U[2], U[3]);
  o[1] = make_uint4(U[4], U[5], U[6], U[7]);
  o[2] = make_uint4(U[8], U[9], U[10], U[11]);
  o[3] = make_uint4(U[12], U[13], U[14], U[15]);
}

// ---------- layer 1 gather: 8 lanes per node ----------
__global__ void k_gather1(const int* __restrict__ offs, const int* __restrict__ cnt,
                          const int* __restrict__ srcs, const float4* __restrict__ eb4,
                          const unsigned int* __restrict__ gb, float* __restrict__ nf1) {
  int tid = blockIdx.x * 256 + threadIdx.x;
  int n = tid >> 3, sl = tid & 7;
  if (n >= NNODES) return;
  int beg = offs[n], cn = cnt[n];
  float M[54];
  #pragma unroll
  for (int i = 0; i < 54; ++i) M[i] = 0.f;
  for (int j = sl; j < cn; j += 8) {
    int p = beg + j;
    int s = srcs[p];
    float4 ebv = eb4[p];
    float bb[9]; make_b(ebv.w, ebv.x, ebv.y, ebv.z, bb);
    const uint4* Gf = (const uint4*)(gb + (size_t)s * 16);
    uint4 u0 = Gf[0], u1 = Gf[1], u2 = Gf[2], u3 = Gf[3];
    unsigned int U[13] = { u0.x, u0.y, u0.z, u0.w, u1.x, u1.y, u1.z, u1.w,
                           u2.x, u2.y, u2.z, u2.w, u3.x };
    float G[26];
    #pragma unroll
    for (int i = 0; i < 13; ++i) { G[2 * i] = bflo(U[i]); G[2 * i + 1] = bfhi(U[i]); }
    #pragma unroll
    for (int u = 0; u < 16; ++u) M[u] += bb[0] * G[u];
    #pragma unroll
    for (int u = 0; u < 6; ++u) {
      float gv = G[16 + u];
      #pragma unroll
      for (int k = 0; k < 3; ++k) M[16 + 3 * u + k] += bb[1 + k] * gv;
    }
    #pragma unroll
    for (int u = 0; u < 4; ++u) {
      float gv = G[22 + u];
      #pragma unroll
      for (int K = 0; K < 5; ++K) M[34 + 5 * u + K] += bb[4 + K] * gv;
    }
  }
  #pragma unroll
  for (int m = 1; m < 8; m <<= 1)
    #pragma unroll
    for (int i = 0; i < 54; ++i) M[i] += __shfl_xor(M[i], m);
  if (sl == 0) {
    const float S23 = 0.20851441405707477f;
    float sc = S23 * rsqrtf((float)cn);
    float4* o4 = (float4*)(nf1 + (size_t)n * 56);
    #pragma unroll
    for (int q = 0; q < 13; ++q)
      o4[q] = make_float4(sc * M[4 * q], sc * M[4 * q + 1], sc * M[4 * q + 2], sc * M[4 * q + 3]);
    o4[13] = make_float4(sc * M[52], sc * M[53], 0.f, 0.f);
  }
}

// ---------- TP2 stage A: per-node t, bf16-packed in consumption order ----------
// packed 72 uints/row (stride 80): O0 w@5w: [s0,p2_0][p2_1,p2_2][q3_0,q3_1][q3_2,q3_3][q3_4,-]
//                                  O2 w@40+6w: [s1,p1_0][p1_1,p1_2][p4_0,p4_1][p4_2,q2_0][q2_1,q2_2][q2_3,q2_4]
//                                  O3 w@58+7w: [s2,q1_0][q1_1,q1_2][q1_3,q1_4][p3_0,p3_1][p3_2,q4_0][q4_1,q4_2][q4_3,q4_4]
__global__ void k_node2t(const float* __restrict__ nf1, const float* __restrict__ w2,
                         unsigned int* __restrict__ tb) {
  __shared__ float W[596];
  for (int i = threadIdx.x; i < 596; i += 256) W[i] = w2[i];
  __syncthreads();
  int n = blockIdx.x * 256 + threadIdx.x;
  if (n >= NNODES) return;
  float A[54];
  const float4* Af = (const float4*)(nf1 + (size_t)n * 56);
  #pragma unroll
  for (int q = 0; q < 13; ++q) { float4 v = Af[q]; A[4*q]=v.x; A[4*q+1]=v.y; A[4*q+2]=v.z; A[4*q+3]=v.w; }
  { float4 v = Af[13]; A[52]=v.x; A[53]=v.y; }

  unsigned int U[72];
  // O0 groups
  #pragma unroll
  for (int w = 0; w < 8; ++w) {
    float s0 = 0;
    #pragma unroll
    for (int u = 0; u < 16; ++u) s0 += A[u] * W[u * 8 + w];
    float p2[3];
    #pragma unroll
    for (int k = 0; k < 3; ++k) { float s = 0; for (int u = 0; u < 6; ++u) s += A[16 + 3 * u + k] * W[316 + 8 * u + w]; p2[k] = s; }
    float q3[5];
    #pragma unroll
    for (int K = 0; K < 5; ++K) { float s = 0; for (int u = 0; u < 4; ++u) s += A[34 + 5 * u + K] * W[472 + 8 * u + w]; q3[K] = s; }
    U[5 * w + 0] = packbf(s0, p2[0]);
    U[5 * w + 1] = packbf(p2[1], p2[2]);
    U[5 * w + 2] = packbf(q3[0], q3[1]);
    U[5 * w + 3] = packbf(q3[2], q3[3]);
    U[5 * w + 4] = packbf(q3[4], 0.f);
  }
  // O2 groups
  #pragma unroll
  for (int w = 0; w < 3; ++w) {
    float s1 = 0;
    #pragma unroll
    for (int u = 0; u < 16; ++u) s1 += A[u] * W[128 + 3 * u + w];
    float p1[3], p4[3];
    #pragma unroll
    for (int k = 0; k < 3; ++k) {
      float a = 0, c = 0;
      #pragma unroll
      for (int u = 0; u < 6; ++u) {
        a += A[16 + 3 * u + k] * W[298 + 3 * u + w];
        c += A[16 + 3 * u + k] * W[394 + 3 * u + w];
      }
      p1[k] = a; p4[k] = c;
    }
    float q2[5];
    #pragma unroll
    for (int K = 0; K < 5; ++K) { float s = 0; for (int u = 0; u < 4; ++u) s += A[34 + 5 * u + K] * W[444 + 3 * u + w]; q2[K] = s; }
    int base = 40 + 6 * w;
    U[base + 0] = packbf(s1, p1[0]);
    U[base + 1] = packbf(p1[1], p1[2]);
    U[base + 2] = packbf(p4[0], p4[1]);
    U[base + 3] = packbf(p4[2], q2[0]);
    U[base + 4] = packbf(q2[1], q2[2]);
    U[base + 5] = packbf(q2[3], q2[4]);
  }
  // O3 groups
  #pragma unroll
  for (int w = 0; w < 2; ++w) {
    float s2 = 0;
    #pragma unroll
    for (int u = 0; u < 16; ++u) s2 += A[u] * W[176 + 2 * u + w];
    float q1[5], q4[5];
    #pragma unroll
    for (int K = 0; K < 5; ++K) {
      float a = 0, c = 0;
      #pragma unroll
      for (int u = 0; u < 4; ++u) {
        a += A[34 + 5 * u + K] * W[436 + 2 * u + w];
        c += A[34 + 5 * u + K] * W[516 + 2 * u + w];
      }
      q1[K] = a; q4[K] = c;
    }
    float p3[3];
    #pragma unroll
    for (int k = 0; k < 3; ++k) { float s = 0; for (int u = 0; u < 6; ++u) s += A[16 + 3 * u + k] * W[382 + 2 * u + w]; p3[k] = s; }
    int base = 58 + 7 * w;
    U[base + 0] = packbf(s2, q1[0]);
    U[base + 1] = packbf(q1[1], q1[2]);
    U[base + 2] = packbf(q1[3], q1[4]);
    U[base + 3] = packbf(p3[0], p3[1]);
    U[base + 4] = packbf(p3[2], q4[0]);
    U[base + 5] = packbf(q4[1], q4[2]);
    U[base + 6] = packbf(q4[3], q4[4]);
  }
  uint4* o = (uint4*)(tb + (size_t)n * 80);
  #pragma unroll
  for (int q = 0; q < 18; ++q)
    o[q] = make_uint4(U[4 * q], U[4 * q + 1], U[4 * q + 2], U[4 * q + 3]);
}

// ---------- TP2 stage B: edge combine (uint4 row loads) + TP3 precompute ----------
__global__ void k_edge2c(const int* __restrict__ offs, const int* __restrict__ cnt,
                         const int* __restrict__ srcs, const float4* __restrict__ eb4,
                         const unsigned int* __restrict__ tb, const float* __restrict__ w3,
                         float* __restrict__ hh) {
  int tid = blockIdx.x * 256 + threadIdx.x;
  int n = tid >> 3, sl = tid & 7;
  if (n >= NNODES) return;
  int beg = offs[n], cn = cnt[n];
  float O0[8], O2[9], O3[10];
  #pragma unroll
  for (int i = 0; i < 8; ++i) O0[i] = 0.f;
  #pragma unroll
  for (int i = 0; i < 9; ++i) O2[i] = 0.f;
  #pragma unroll
  for (int i = 0; i < 10; ++i) O3[i] = 0.f;

  const float I3 = 0.5773502691896258f, I5 = 0.4472135954999579f;
  const float CA = 0.18257418583505536f, CB = 0.31622776601683794f, CC = 0.3651483716701107f;
  const float P = 0.2390457218668787f, Q = 0.2070196678027063f, R = 0.1195228609334394f;

  for (int j = sl; j < cn; j += 8) {
    int p = beg + j;
    int s = srcs[p];
    // 18 back-to-back uint4 loads: whole 288B row in flight at once
    const uint4* T4 = (const uint4*)(tb + (size_t)s * 80);
    uint4 Qv[18];
    #pragma unroll
    for (int i = 0; i < 18; ++i) Qv[i] = T4[i];
    float4 ebv = eb4[p];
    float b[9]; make_b(ebv.w, ebv.x, ebv.y, ebv.z, b);

    unsigned int TT[72];
    #pragma unroll
    for (int i = 0; i < 18; ++i) {
      TT[4 * i] = Qv[i].x; TT[4 * i + 1] = Qv[i].y; TT[4 * i + 2] = Qv[i].z; TT[4 * i + 3] = Qv[i].w;
    }

    float CBb1_0 = CB * b[1], CBb1_1 = CB * b[2], CBb1_2 = CB * b[3];
    float CAb1_0 = CA * b[1], CAb1_2 = CA * b[3], CCb1_1 = CC * b[2];
    float c121_00 = -CA * b[6] - CB * b[8], c121_01 = CB * b[5], c121_02 = CB * b[4];
    float c121_11 = CC * b[6], c121_12 = CB * b[7], c121_22 = -CA * b[6] + CB * b[8];
    float Pb2_0 = P * b[4], Pb2_2 = P * b[6], Pb2_4 = P * b[8];
    float Qb2_0 = Q * b[4], Qb2_1 = Q * b[5], Qb2_3 = Q * b[7], Qb2_4 = Q * b[8];
    float Rb2_1 = R * b[5], Rb2_2 = R * b[6], Rb2_3 = R * b[7];

    // O0 (8 groups @ 5 uints)
    #pragma unroll
    for (int w = 0; w < 8; ++w) {
      unsigned int u0 = TT[5 * w], u1 = TT[5 * w + 1], u2 = TT[5 * w + 2], u3 = TT[5 * w + 3], u4 = TT[5 * w + 4];
      O0[w] += b[0] * bflo(u0)
             + I3 * (bfhi(u0) * b[1] + bflo(u1) * b[2] + bfhi(u1) * b[3])
             + I5 * (bflo(u2) * b[4] + bfhi(u2) * b[5] + bflo(u3) * b[6]
                   + bfhi(u3) * b[7] + bflo(u4) * b[8]);
    }
    // O2 (3 groups @ 6 uints, base 40+6w)
    #pragma unroll
    for (int w = 0; w < 3; ++w) {
      unsigned int u0 = TT[40 + 6 * w], u1 = TT[41 + 6 * w], u2 = TT[42 + 6 * w],
                   u3 = TT[43 + 6 * w], u4 = TT[44 + 6 * w], u5 = TT[45 + 6 * w];
      float ta  = bflo(u0);
      float tb0 = bfhi(u0), tb1 = bflo(u1), tb2 = bfhi(u1);
      float tc0 = bflo(u2), tc1 = bfhi(u2), tc2 = bflo(u3);
      float td0 = bfhi(u3), td1 = bflo(u4), td2 = bfhi(u4), td3 = bflo(u5), td4 = bfhi(u5);
      O2[3 * w + 0] += I3 * (b[1] * ta + b[0] * tb0)
                     + tc0 * c121_00 + tc1 * c121_01 + tc2 * c121_02
                     + td0 * CBb1_2 + td1 * CBb1_1 - td2 * CAb1_0 - td4 * CBb1_0;
      O2[3 * w + 1] += I3 * (b[2] * ta + b[0] * tb1)
                     + tc0 * c121_01 + tc1 * c121_11 + tc2 * c121_12
                     + td1 * CBb1_0 + td2 * CCb1_1 + td3 * CBb1_2;
      O2[3 * w + 2] += I3 * (b[3] * ta + b[0] * tb2)
                     + tc0 * c121_02 + tc1 * c121_12 + tc2 * c121_22
                     + td0 * CBb1_0 - td2 * CAb1_2 + td3 * CBb1_1 + td4 * CBb1_2;
    }
    // O3 (2 groups @ 7 uints, base 58+7w)
    #pragma unroll
    for (int w = 0; w < 2; ++w) {
      unsigned int u0 = TT[58 + 7 * w], u1 = TT[59 + 7 * w], u2 = TT[60 + 7 * w], u3 = TT[61 + 7 * w],
                   u4 = TT[62 + 7 * w], u5 = TT[63 + 7 * w], u6 = TT[64 + 7 * w];
      float ta  = bflo(u0);
      float tb0 = bfhi(u0), tb1 = bflo(u1), tb2 = bfhi(u1), tb3 = bflo(u2), tb4 = bfhi(u2);
      float tc0 = bflo(u3), tc1 = bfhi(u3), tc2 = bflo(u4);
      float td0 = bfhi(u4), td1 = bflo(u5), td2 = bfhi(u5), td3 = bflo(u6), td4 = bfhi(u6);
      O3[5 * w + 0] += I5 * (b[4] * ta + b[0] * tb0)
                     + tc0 * CBb1_2 + tc2 * CBb1_0
                     - Pb2_2 * td0 + Qb2_3 * td1 - Pb2_0 * td2 + Qb2_1 * td3;
      O3[5 * w + 1] += I5 * (b[5] * ta + b[0] * tb1)
                     + tc0 * CBb1_1 + tc1 * CBb1_0
                     + Qb2_3 * td0 + (Rb2_2 - Qb2_4) * td1 + Rb2_1 * td2 + Qb2_0 * td3 - Qb2_1 * td4;
      O3[5 * w + 2] += I5 * (b[6] * ta + b[0] * tb2)
                     - tc0 * CAb1_0 + tc1 * CCb1_1 - tc2 * CAb1_2
                     - Pb2_0 * td0 + Rb2_1 * td1 + Pb2_2 * td2 + Rb2_3 * td3 - Pb2_4 * td4;
      O3[5 * w + 3] += I5 * (b[7] * ta + b[0] * tb3)
                     + tc1 * CBb1_2 + tc2 * CBb1_1
                     + Qb2_1 * td0 + Qb2_0 * td1 + Rb2_3 * td2 + (Rb2_2 + Qb2_4) * td3 + Qb2_3 * td4;
      O3[5 * w + 4] += I5 * (b[8] * ta + b[0] * tb4)
                     - tc0 * CBb1_0 + tc2 * CBb1_2
                     - Qb2_1 * td1 - Pb2_4 * td2 + Qb2_3 * td3 - Pb2_2 * td4;
    }
  }

  #pragma unroll
  for (int m = 1; m < 8; m <<= 1) {
    #pragma unroll
    for (int i = 0; i < 8; ++i) O0[i] += __shfl_xor(O0[i], m);
    #pragma unroll
    for (int i = 0; i < 9; ++i) O2[i] += __shfl_xor(O2[i], m);
    #pragma unroll
    for (int i = 0; i < 10; ++i) O3[i] += __shfl_xor(O3[i], m);
  }

  if (sl == 0) {
    const float S26 = 0.19611613513818404f, S14 = 0.2672612419124244f, S8 = 0.35355339059327373f;
    const float S13 = 0.2773500981126146f;
    float di = rsqrtf((float)cn);
    float F[27];
    #pragma unroll
    for (int w = 0; w < 8; ++w) F[w] = S26 * di * O0[w];
    #pragma unroll
    for (int i = 0; i < 9; ++i) F[8 + i] = S14 * di * O2[i];
    #pragma unroll
    for (int i = 0; i < 10; ++i) F[17 + i] = S8 * di * O3[i];

    float h[9];
    float t0 = 0;
    #pragma unroll
    for (int u = 0; u < 8; ++u) t0 += F[u] * w3[u];
    h[0] = S13 * t0;
    #pragma unroll
    for (int jj = 0; jj < 3; ++jj) {
      float s1 = 0;
      #pragma unroll
      for (int u = 0; u < 3; ++u) s1 += F[8 + 3 * u + jj] * w3[8 + u];
      h[1 + jj] = S13 * I3 * s1;
    }
    #pragma unroll
    for (int K = 0; K < 5; ++K)
      h[4 + K] = S13 * I5 * (F[17 + K] * w3[11] + F[22 + K] * w3[12]);

    float4* o4 = (float4*)(hh + (size_t)n * 16);
    o4[0] = make_float4(h[0], h[1], h[2], h[3]);
    o4[1] = make_float4(h[4], h[5], h[6], h[7]);
    o4[2] = make_float4(h[8], 0.f, 0.f, 0.f);
  }
}

// ---------- layer 3 gather + molecule reduce ----------
__global__ void k_gather3(const int* __restrict__ offs, const int* __restrict__ cnt,
                          const int* __restrict__ srcs, const float4* __restrict__ eb4,
                          const float* __restrict__ hh, const int* __restrict__ batch,
                          float* __restrict__ out) {
  int tid = blockIdx.x * 256 + threadIdx.x;
  int n = tid >> 3, sl = tid & 7;
  if (n >= NNODES) return;
  int beg = offs[n], cn = cnt[n];
  float v = 0.f;
  for (int j = sl; j < cn; j += 8) {
    int p = beg + j;
    int s = srcs[p];
    float4 ebv = eb4[p];
    float b[9]; make_b(ebv.w, ebv.x, ebv.y, ebv.z, b);
    const float4* Hf = (const float4*)(hh + (size_t)s * 16);
    float4 hA = Hf[0], hB = Hf[1];
    float h8 = Hf[2].x;
    v += b[0] * hA.x + b[1] * hA.y + b[2] * hA.z + b[3] * hA.w
       + b[4] * hB.x + b[5] * hB.y + b[6] * hB.z + b[7] * hB.w
       + b[8] * h8;
  }
  #pragma unroll
  for (int m = 1; m < 8; m <<= 1) v += __shfl_xor(v, m);
  if (sl == 0) {
    float di = rsqrtf((float)cn);
    unsafeAtomicAdd(out + batch[n], v * di * 0.2f);  // /sqrt(apm)=/5
  }
}

extern "C" void kernel_launch(void* const* d_in, const int* in_sizes, int n_in,
                              void* d_out, int out_size, void* d_ws, size_t ws_size,
                              hipStream_t stream) {
  const float* positions = (const float*)d_in[0];
  const float* x         = (const float*)d_in[1];
  const float* edge_attr = (const float*)d_in[2];
  const float* lin_w     = (const float*)d_in[3];
  const float* lin_b     = (const float*)d_in[4];
  const float* w_tp1     = (const float*)d_in[5];
  const float* w_tp2     = (const float*)d_in[6];
  const float* w_tp3     = (const float*)d_in[7];
  const int*   edge_src  = (const int*)d_in[8];
  const int*   edge_dst  = (const int*)d_in[9];
  const int*   batch     = (const int*)d_in[10];
  float* out = (float*)d_out;

  int*   cnt  = (int*)d_ws + OFF_CNT;
  int*   offs = (int*)d_ws + OFF_OFFS;
  int*   curs = (int*)d_ws + OFF_CURS;
  int*   bsum = (int*)d_ws + OFF_BSUM;
  int*   srcs = (int*)d_ws + OFF_SRCS;
  float4* eb4 = (float4*)((float*)d_ws + OFF_EB4);
  unsigned int* gb = (unsigned int*)((float*)d_ws + OFF_GB);
  float* nf1  = (float*)d_ws + OFF_NF1;
  unsigned int* tb = (unsigned int*)((float*)d_ws + OFF_TB);
  float* hh   = (float*)d_ws + OFF_HH;

  hipMemsetAsync(cnt, 0, NNODES * sizeof(int), stream);
  hipMemsetAsync(out, 0, (size_t)out_size * sizeof(float), stream);

  dim3 blk256(256);
  dim3 gEdge((NEDGES + 255) / 256);
  dim3 gNode256((NNODES + 255) / 256);
  dim3 gCoop((NNODES * 8 + 255) / 256);

  k_count<<<gEdge, blk256, 0, stream>>>(edge_dst, cnt);
  k_scanA<<<dim3(NBLK), blk256, 0, stream>>>(cnt, offs, bsum);
  k_scanB<<<dim3(1), blk256, 0, stream>>>(bsum);
  k_scanC<<<dim3(NBLK), blk256, 0, stream>>>(offs, curs, bsum);
  k_fill<<<gEdge, blk256, 0, stream>>>(positions, edge_attr, edge_src, edge_dst, curs, srcs, eb4);
  k_node1<<<gNode256, blk256, 0, stream>>>(x, lin_w, lin_b, w_tp1, gb);
  k_gather1<<<gCoop, blk256, 0, stream>>>(offs, cnt, srcs, eb4, gb, nf1);
  k_node2t<<<gNode256, blk256, 0, stream>>>(nf1, w_tp2, tb);
  k_edge2c<<<gCoop, blk256, 0, stream>>>(offs, cnt, srcs, eb4, tb, w_tp3, hh);
  k_gather3<<<gCoop, blk256, 0, stream>>>(offs, cnt, srcs, eb4, hh, batch, out);
}